// Round 2
// baseline (1687.708 us; speedup 1.0000x reference)
//
#include <hip/hip_runtime.h>
#include <cstdint>
#include <cstddef>

// ---------------------------------------------------------------------------
// RPN pipeline, fp64-accurate (ordering-critical: top-k rank + NMS decisions).
// fp32 inputs; all reductions accumulate in double (fp32*fp32 exact in f64).
// ---------------------------------------------------------------------------

typedef unsigned long long ull;

#define NANCH 9
#define NPIX  2500      // 50*50
#define CIN   512
#define COUT  512
#define KTOT  4608      // 512*9
#define KSEG  2304      // KTOT/2
#define NBOX  22500     // 2500*9
#define TOPK1 10000
#define TOPK2 2000
#define WORDS 157       // ceil(10000/64)

// ---------------- conv 3x3 as implicit-im2col GEMM, fp64 accum -------------
// grid (40 p-tiles, 8 co-tiles, 2 k-segments), block 256.
// Writes raw partial sums part[z][co][p] (bias+relu applied in heads).
__global__ __launch_bounds__(256) void conv_gemm(const float* __restrict__ feat,
                                                 const float* __restrict__ w,
                                                 double* __restrict__ part) {
  const int p0  = blockIdx.x * 64;
  const int co0 = blockIdx.y * 64;
  const int z   = blockIdx.z;
  const int kseg0 = z * KSEG;
  __shared__ float As[16][68];   // [k][co], padded to 68 (16B-aligned rows)
  __shared__ float Bs[16][68];   // [k][p]
  const int tid = threadIdx.x;
  const int tx = tid & 15, ty = tid >> 4;       // compute: p dir, co dir
  const int coA = tid >> 2, kA = (tid & 3) * 4; // A staging
  const int plB = tid & 63, kB0 = tid >> 6;     // B staging
  const int pB = p0 + plB;
  const int py = pB / 50, px = pB - py * 50;
  double acc[4][4];
#pragma unroll
  for (int i = 0; i < 4; ++i)
#pragma unroll
    for (int j = 0; j < 4; ++j) acc[i][j] = 0.0;

  for (int k0 = 0; k0 < KSEG; k0 += 16) {
    // A: weights are already [co][k] contiguous (OIHW with k = ci*9+ky*3+kx)
    float4 a4 = *(const float4*)(w + (size_t)(co0 + coA) * KTOT + (kseg0 + k0 + kA));
    // B: on-the-fly im2col (exact copy of fp32 feat values, zero padding)
    float bv[4];
#pragma unroll
    for (int jj = 0; jj < 4; ++jj) {
      int k = kseg0 + k0 + kB0 + 4 * jj;
      int ci = k / 9;
      int r  = k - ci * 9;
      int ky = r / 3;
      int kx = r - ky * 3;
      int yy = py + ky - 1, xx = px + kx - 1;
      float v = 0.0f;
      if (pB < NPIX && yy >= 0 && yy < 50 && xx >= 0 && xx < 50)
        v = feat[ci * NPIX + yy * 50 + xx];
      bv[jj] = v;
    }
    __syncthreads();
    As[kA + 0][coA] = a4.x;
    As[kA + 1][coA] = a4.y;
    As[kA + 2][coA] = a4.z;
    As[kA + 3][coA] = a4.w;
#pragma unroll
    for (int jj = 0; jj < 4; ++jj) Bs[kB0 + 4 * jj][plB] = bv[jj];
    __syncthreads();
#pragma unroll
    for (int k = 0; k < 16; ++k) {
      float4 av = *(const float4*)&As[k][ty * 4];
      float4 b4 = *(const float4*)&Bs[k][tx * 4];
      double ad[4] = {(double)av.x, (double)av.y, (double)av.z, (double)av.w};
      double bd[4] = {(double)b4.x, (double)b4.y, (double)b4.z, (double)b4.w};
#pragma unroll
      for (int i = 0; i < 4; ++i)
#pragma unroll
        for (int j = 0; j < 4; ++j) acc[i][j] += ad[i] * bd[j];
    }
  }
#pragma unroll
  for (int i = 0; i < 4; ++i) {
    int co = co0 + ty * 4 + i;
#pragma unroll
    for (int j = 0; j < 4; ++j) {
      int p = p0 + tx * 4 + j;
      if (p < NPIX)
        part[(size_t)z * COUT * NPIX + (size_t)co * NPIX + p] = acc[i][j];
    }
  }
}

// ---------------- heads: relu(conv)+bias, cls+box 1x1 convs, decode --------
__global__ __launch_bounds__(256) void heads_kernel(
    const double* __restrict__ part, const float* __restrict__ rpn_b,
    const float* __restrict__ cls_w, const float* __restrict__ cls_b,
    const float* __restrict__ box_w, const float* __restrict__ box_b,
    double* __restrict__ logits, double* __restrict__ boxesAll,
    float* __restrict__ out_cls) {
  int p = blockIdx.x * blockDim.x + threadIdx.x;
  bool act = p < NPIX;
  int pp = act ? p : 0;
  double accC[9];
  double accB[36];
#pragma unroll
  for (int a = 0; a < 9; ++a) accC[a] = 0.0;
#pragma unroll
  for (int c = 0; c < 36; ++c) accB[c] = 0.0;
  const double* part1 = part + (size_t)COUT * NPIX;
  for (int co = 0; co < CIN; ++co) {
    double v = part[(size_t)co * NPIX + pp] + part1[(size_t)co * NPIX + pp] +
               (double)rpn_b[co];
    v = v > 0.0 ? v : 0.0;
#pragma unroll
    for (int a = 0; a < 9; ++a) accC[a] += (double)cls_w[a * CIN + co] * v;
#pragma unroll
    for (int c = 0; c < 36; ++c) accB[c] += (double)box_w[c * CIN + co] * v;
  }
  if (!act) return;
  int y = p / 50, x = p - y * 50;
  double sx = 16.0 * (double)x, sy = 16.0 * (double)y;
  const double scs[3] = {128.0, 256.0, 512.0};
  const double ars[3] = {0.5, 1.0, 2.0};
#pragma unroll
  for (int a = 0; a < 9; ++a) {
    double ar = ars[a / 3], sc = scs[a - (a / 3) * 3];
    double hr = sqrt(ar), wr = 1.0 / hr;
    double wv = wr * sc, hv = hr * sc;
    // jnp.round == round-half-even == rint under default rounding mode
    double bx0 = rint(-wv * 0.5), by0 = rint(-hv * 0.5);
    double bx1 = rint(wv * 0.5), by1 = rint(hv * 0.5);
    double a0 = sx + bx0, a1 = sy + by0, a2 = sx + bx1, a3 = sy + by1;
    double wA = a2 - a0, hA = a3 - a1;
    double cx = a0 + 0.5 * wA, cy = a1 + 0.5 * hA;
    double dx = accB[a * 4 + 0] + (double)box_b[a * 4 + 0];
    double dy = accB[a * 4 + 1] + (double)box_b[a * 4 + 1];
    double dw = accB[a * 4 + 2] + (double)box_b[a * 4 + 2];
    double dh = accB[a * 4 + 3] + (double)box_b[a * 4 + 3];
    double pcx = wA * dx + cx, pcy = hA * dy + cy;
    double pw = exp(dw) * wA, ph = exp(dh) * hA;
    double b0 = pcx - 0.5 * pw, b1 = pcy - 0.5 * ph;
    double b2 = pcx + 0.5 * pw, b3 = pcy + 0.5 * ph;
    b0 = fmin(fmax(b0, 0.0), 800.0);
    b1 = fmin(fmax(b1, 0.0), 800.0);
    b2 = fmin(fmax(b2, 0.0), 800.0);
    b3 = fmin(fmax(b3, 0.0), 800.0);
    int idx = p * 9 + a;
    boxesAll[(size_t)idx * 4 + 0] = b0;
    boxesAll[(size_t)idx * 4 + 1] = b1;
    boxesAll[(size_t)idx * 4 + 2] = b2;
    boxesAll[(size_t)idx * 4 + 3] = b3;
    double L = accC[a] + (double)cls_b[a];
    logits[idx] = L;
    out_cls[idx] = (float)L;
  }
}

// ---------------- exact stable descending rank (== jax.lax.top_k order) ---
__global__ __launch_bounds__(256) void rank_count(const double* __restrict__ logits,
                                                  int* __restrict__ ranks) {
  __shared__ double Ls[2048];
  int i = blockIdx.x * 256 + threadIdx.x;
  int j0 = blockIdx.y * 2048;
  int jn = NBOX - j0;
  if (jn > 2048) jn = 2048;
  for (int t = threadIdx.x; t < jn; t += 256) Ls[t] = logits[j0 + t];
  __syncthreads();
  if (i >= NBOX) return;
  double Li = logits[i];
  int cnt = 0;
  for (int t = 0; t < jn; ++t) {
    double Lj = Ls[t];
    int j = j0 + t;
    cnt += (Lj > Li || (Lj == Li && j < i)) ? 1 : 0;
  }
  atomicAdd(&ranks[i], cnt);
}

__global__ __launch_bounds__(256) void scatter_topk(const double* __restrict__ logits,
                                                    const double* __restrict__ boxesAll,
                                                    const int* __restrict__ ranks,
                                                    double* __restrict__ sLog,
                                                    double* __restrict__ sBox) {
  int i = blockIdx.x * 256 + threadIdx.x;
  if (i >= NBOX) return;
  int r = ranks[i];
  if (r < TOPK1) {
    sLog[r] = logits[i];
    sBox[(size_t)r * 4 + 0] = boxesAll[(size_t)i * 4 + 0];
    sBox[(size_t)r * 4 + 1] = boxesAll[(size_t)i * 4 + 1];
    sBox[(size_t)r * 4 + 2] = boxesAll[(size_t)i * 4 + 2];
    sBox[(size_t)r * 4 + 3] = boxesAll[(size_t)i * 4 + 3];
  }
}

// ---------------- pairwise IoU suppression bitmask (upper triangle) --------
// grid (157 i-tiles, 40 word-tiles), block 256 = 64 i x 4 words.
__global__ __launch_bounds__(256) void iou_mask(const double* __restrict__ sb,
                                                ull* __restrict__ mask) {
  const int it = blockIdx.x;
  const int wt = blockIdx.y;
  if (wt * 4 + 3 < it) return;  // block only needed for words >= i/64
  __shared__ double ib[64][4];
  __shared__ double jb[256][4];
  const int tid = threadIdx.x;
  {
    int ii = it * 64 + (tid >> 2);
    int d = tid & 3;
    ib[tid >> 2][d] = (ii < TOPK1) ? sb[(size_t)ii * 4 + d] : 0.0;
  }
  for (int t = tid; t < 1024; t += 256) {
    int jj = wt * 256 + (t >> 2);
    jb[t >> 2][t & 3] = (jj < TOPK1) ? sb[(size_t)jj * 4 + (t & 3)] : 0.0;
  }
  __syncthreads();
  const int il = tid & 63, wl = tid >> 6;
  const int i = it * 64 + il;
  const int word = wt * 4 + wl;
  // NOTE: word can reach 159 (40*4-1) but only 157 words exist. The missing
  // `word >= WORDS` guard in R0 wrote zeros into row i+1's words 0..2 (OOB
  // within the row) — a write race that corrupted suppression bits among the
  // top ~192 ranked boxes. Guard added.
  if (i >= TOPK1 || word >= WORDS || word < (i >> 6)) return;
  const double x0 = ib[il][0], y0 = ib[il][1], x1 = ib[il][2], y1 = ib[il][3];
  const double areai = (x1 - x0) * (y1 - y0);
  ull bits = 0;
  const int jbase = word * 64;
  for (int b = 0; b < 64; ++b) {
    int j = jbase + b;
    if (j <= i || j >= TOPK1) continue;
    int jl = wl * 64 + b;
    double u0 = jb[jl][0], u1 = jb[jl][1], u2 = jb[jl][2], u3 = jb[jl][3];
    double xl = fmax(x0, u0), yt = fmax(y0, u1);
    double xr = fmin(x1, u2), yb = fmin(y1, u3);
    double iw = xr - xl, ih = yb - yt;
    iw = iw > 0.0 ? iw : 0.0;
    ih = ih > 0.0 ? ih : 0.0;
    double inter = iw * ih;
    double aj = (u2 - u0) * (u3 - u1);
    double un = areai + aj - inter;
    // reference: inter/un > 0.7 (0/0 -> NaN -> false). Multiply form matches.
    if (inter > 0.7 * un) bits |= 1ull << b;
  }
  mask[(size_t)i * WORDS + word] = bits;
}

// ---------------- sequential greedy-NMS scan, single wave ------------------
// Lane l owns removal-mask words {l, 64+l, 128+l} in registers.
__global__ __launch_bounds__(64) void nms_scan(const ull* __restrict__ mask,
                                               ull* __restrict__ keepwords) {
  const int l = threadIdx.x;
  ull r0 = 0, r1 = 0, r2 = 0;
  __shared__ int klist[64];
  for (int g = 0; g < WORDS; ++g) {
    ull rw = (g < 64) ? r0 : (g < 128 ? r1 : r2);
    ull cur = __shfl(rw, g & 63);  // uniform: remv word g so far
    int i = g * 64 + l;
    ull mrow = (i < TOPK1) ? mask[(size_t)i * WORDS + g] : 0ull;
    // resolve intra-group: iterate only over still-unsuppressed bits
    ull rem = ~cur;
    if (g == WORDS - 1) rem &= 0xFFFFull;  // only 10000 boxes (16 in last grp)
    while (rem) {
      int b = __ffsll((long long)rem) - 1;
      ull m = __shfl(mrow, b);  // row (g*64+b)'s intra word (bits > b only)
      cur |= m;
      ull above = (b == 63) ? 0ull : ~((2ull << b) - 1ull);
      rem = (~cur) & rem & above;
    }
    ull validm = (g == WORDS - 1) ? 0xFFFFull : ~0ull;
    ull kb = (~cur) & validm;
    if (l == (g & 63)) {
      if (g < 64) r0 = cur;
      else if (g < 128) r1 = cur;
      else r2 = cur;
    }
    if (l == 0) keepwords[g] = kb;
    int nk = __popcll(kb);
    if ((kb >> l) & 1ull) {
      ull below = (l == 0) ? 0ull : (kb & ((1ull << l) - 1ull));
      klist[__popcll(below)] = g * 64 + l;
    }
    __syncthreads();
    // OR kept rows' words (> g) into distributed removal mask, 4-row batches
    const int w2 = 64 + l, w3 = 128 + l;
    const bool u1 = (l > g);
    const bool u2 = (w2 > g) && (w2 < WORDS);
    const bool u3 = (w3 > g) && (w3 < WORDS);
    for (int t = 0; t < nk; t += 4) {
      ull a0 = 0, a1 = 0, a2 = 0, b0 = 0, b1 = 0, b2 = 0;
      ull c0 = 0, c1 = 0, c2 = 0, d0 = 0, d1 = 0, d2 = 0;
      {
        const ull* row = mask + (size_t)klist[t] * WORDS;
        if (u1) a0 = row[l];
        if (u2) a1 = row[w2];
        if (u3) a2 = row[w3];
      }
      if (t + 1 < nk) {
        const ull* row = mask + (size_t)klist[t + 1] * WORDS;
        if (u1) b0 = row[l];
        if (u2) b1 = row[w2];
        if (u3) b2 = row[w3];
      }
      if (t + 2 < nk) {
        const ull* row = mask + (size_t)klist[t + 2] * WORDS;
        if (u1) c0 = row[l];
        if (u2) c1 = row[w2];
        if (u3) c2 = row[w3];
      }
      if (t + 3 < nk) {
        const ull* row = mask + (size_t)klist[t + 3] * WORDS;
        if (u1) d0 = row[l];
        if (u2) d1 = row[w2];
        if (u3) d2 = row[w3];
      }
      r0 |= a0 | b0 | c0 | d0;
      r1 |= a1 | b1 | c1 | d1;
      r2 |= a2 | b2 | c2 | d2;
    }
    __syncthreads();
  }
}

// ---------------- compact kept boxes, sigmoid scores, write output ---------
__global__ __launch_bounds__(256) void finalize_kernel(const ull* __restrict__ keepwords,
                                                       const double* __restrict__ sBox,
                                                       const double* __restrict__ sLog,
                                                       float* __restrict__ out) {
  __shared__ int pref[WORDS];
  int t = threadIdx.x;
  if (t == 0) {
    int s = 0;
    for (int w = 0; w < WORDS; ++w) {
      pref[w] = s;
      s += __popcll(keepwords[w]);
    }
  }
  __syncthreads();
  if (t < WORDS) {
    ull kb = keepwords[t];
    int base = pref[t];
    while (kb) {
      int b = __ffsll((long long)kb) - 1;
      kb &= kb - 1;
      if (base < TOPK2) {
        int i = t * 64 + b;
        out[base * 4 + 0] = (float)sBox[(size_t)i * 4 + 0];
        out[base * 4 + 1] = (float)sBox[(size_t)i * 4 + 1];
        out[base * 4 + 2] = (float)sBox[(size_t)i * 4 + 2];
        out[base * 4 + 3] = (float)sBox[(size_t)i * 4 + 3];
        double L = sLog[i];
        out[TOPK2 * 4 + base] = (float)(1.0 / (1.0 + exp(-L)));
      }
      ++base;
    }
  }
}

// ---------------------------------------------------------------------------
extern "C" void kernel_launch(void* const* d_in, const int* in_sizes, int n_in,
                              void* d_out, int out_size, void* d_ws, size_t ws_size,
                              hipStream_t stream) {
  // inputs: 0 image(unused) 1 feat 2 rpn_w 3 rpn_b 4 cls_w 5 cls_b 6 box_w 7 box_b
  const float* feat  = (const float*)d_in[1];
  const float* rpn_w = (const float*)d_in[2];
  const float* rpn_b = (const float*)d_in[3];
  const float* cls_w = (const float*)d_in[4];
  const float* cls_b = (const float*)d_in[5];
  const float* box_w = (const float*)d_in[6];
  const float* box_b = (const float*)d_in[7];
  float* out = (float*)d_out;

  // workspace layout (bytes, all 16B aligned); total ~34.44 MB
  char* ws = (char*)d_ws;
  double* part     = (double*)(ws);                 // 2*512*2500*8 = 20,480,000
  double* logits   = (double*)(ws + 20480000);      // 22500*8     =    180,000
  double* boxesAll = (double*)(ws + 20660000);      // 22500*4*8   =    720,000
  int*    ranks    = (int*)   (ws + 21380000);      // 22500*4     =     90,000
  double* sBox     = (double*)(ws + 21470000);      // 10000*4*8   =    320,000
  double* sLog     = (double*)(ws + 21790000);      // 10000*8     =     80,000
  ull*    mask     = (ull*)   (ws + 21870000);      // 10000*157*8 = 12,560,000
  ull*    keepw    = (ull*)   (ws + 34430000);      // 157*8       =      1,256

  hipMemsetAsync(d_out, 0, (TOPK2 * 4 + TOPK2) * sizeof(float), stream);
  hipMemsetAsync(ranks, 0, NBOX * sizeof(int), stream);

  conv_gemm<<<dim3(40, 8, 2), 256, 0, stream>>>(feat, rpn_w, part);
  heads_kernel<<<10, 256, 0, stream>>>(part, rpn_b, cls_w, cls_b, box_w, box_b,
                                       logits, boxesAll, out + TOPK2 * 5);
  rank_count<<<dim3(88, 11), 256, 0, stream>>>(logits, ranks);
  scatter_topk<<<88, 256, 0, stream>>>(logits, boxesAll, ranks, sLog, sBox);
  iou_mask<<<dim3(WORDS, 40), 256, 0, stream>>>(sBox, mask);
  nms_scan<<<1, 64, 0, stream>>>(mask, keepw);
  finalize_kernel<<<1, 256, 0, stream>>>(keepw, sBox, sLog, out);
}

// Round 3
// 1630.836 us; speedup vs baseline: 1.0349x; 1.0349x over previous
//
#include <hip/hip_runtime.h>
#include <cstdint>
#include <cstddef>

// ---------------------------------------------------------------------------
// RPN pipeline, fp64-accurate (ordering-critical: top-k rank + NMS decisions).
// fp32 inputs; all reductions accumulate in double (fp32*fp32 exact in f64).
// ---------------------------------------------------------------------------

typedef unsigned long long ull;

#define NANCH 9
#define NPIX  2500      // 50*50
#define CIN   512
#define COUT  512
#define KTOT  4608      // 512*9
#define KSEG  2304      // KTOT/2
#define NBOX  22500     // 2500*9
#define TOPK1 10000
#define TOPK2 2000
#define WORDS 157       // ceil(10000/64)

// ---------------- conv 3x3 as implicit-im2col GEMM, fp64 accum -------------
// grid (40 p-tiles, 8 co-tiles, 2 k-segments), block 256.
// Writes raw partial sums part[z][co][p] (bias+relu applied in heads).
__global__ __launch_bounds__(256) void conv_gemm(const float* __restrict__ feat,
                                                 const float* __restrict__ w,
                                                 double* __restrict__ part) {
  const int p0  = blockIdx.x * 64;
  const int co0 = blockIdx.y * 64;
  const int z   = blockIdx.z;
  const int kseg0 = z * KSEG;
  __shared__ float As[16][68];   // [k][co], padded to 68 (16B-aligned rows)
  __shared__ float Bs[16][68];   // [k][p]
  const int tid = threadIdx.x;
  const int tx = tid & 15, ty = tid >> 4;       // compute: p dir, co dir
  const int coA = tid >> 2, kA = (tid & 3) * 4; // A staging
  const int plB = tid & 63, kB0 = tid >> 6;     // B staging
  const int pB = p0 + plB;
  const int py = pB / 50, px = pB - py * 50;
  double acc[4][4];
#pragma unroll
  for (int i = 0; i < 4; ++i)
#pragma unroll
    for (int j = 0; j < 4; ++j) acc[i][j] = 0.0;

  for (int k0 = 0; k0 < KSEG; k0 += 16) {
    // A: weights are already [co][k] contiguous (OIHW with k = ci*9+ky*3+kx)
    float4 a4 = *(const float4*)(w + (size_t)(co0 + coA) * KTOT + (kseg0 + k0 + kA));
    // B: on-the-fly im2col (exact copy of fp32 feat values, zero padding)
    float bv[4];
#pragma unroll
    for (int jj = 0; jj < 4; ++jj) {
      int k = kseg0 + k0 + kB0 + 4 * jj;
      int ci = k / 9;
      int r  = k - ci * 9;
      int ky = r / 3;
      int kx = r - ky * 3;
      int yy = py + ky - 1, xx = px + kx - 1;
      float v = 0.0f;
      if (pB < NPIX && yy >= 0 && yy < 50 && xx >= 0 && xx < 50)
        v = feat[ci * NPIX + yy * 50 + xx];
      bv[jj] = v;
    }
    __syncthreads();
    As[kA + 0][coA] = a4.x;
    As[kA + 1][coA] = a4.y;
    As[kA + 2][coA] = a4.z;
    As[kA + 3][coA] = a4.w;
#pragma unroll
    for (int jj = 0; jj < 4; ++jj) Bs[kB0 + 4 * jj][plB] = bv[jj];
    __syncthreads();
#pragma unroll
    for (int k = 0; k < 16; ++k) {
      float4 av = *(const float4*)&As[k][ty * 4];
      float4 b4 = *(const float4*)&Bs[k][tx * 4];
      double ad[4] = {(double)av.x, (double)av.y, (double)av.z, (double)av.w};
      double bd[4] = {(double)b4.x, (double)b4.y, (double)b4.z, (double)b4.w};
#pragma unroll
      for (int i = 0; i < 4; ++i)
#pragma unroll
        for (int j = 0; j < 4; ++j) acc[i][j] += ad[i] * bd[j];
    }
  }
#pragma unroll
  for (int i = 0; i < 4; ++i) {
    int co = co0 + ty * 4 + i;
#pragma unroll
    for (int j = 0; j < 4; ++j) {
      int p = p0 + tx * 4 + j;
      if (p < NPIX)
        part[(size_t)z * COUT * NPIX + (size_t)co * NPIX + p] = acc[i][j];
    }
  }
}

// ---------------- heads: relu(conv)+bias, cls+box 1x1 convs, decode --------
__global__ __launch_bounds__(256) void heads_kernel(
    const double* __restrict__ part, const float* __restrict__ rpn_b,
    const float* __restrict__ cls_w, const float* __restrict__ cls_b,
    const float* __restrict__ box_w, const float* __restrict__ box_b,
    double* __restrict__ logits, double* __restrict__ boxesAll,
    float* __restrict__ out_cls) {
  int p = blockIdx.x * blockDim.x + threadIdx.x;
  bool act = p < NPIX;
  int pp = act ? p : 0;
  double accC[9];
  double accB[36];
#pragma unroll
  for (int a = 0; a < 9; ++a) accC[a] = 0.0;
#pragma unroll
  for (int c = 0; c < 36; ++c) accB[c] = 0.0;
  const double* part1 = part + (size_t)COUT * NPIX;
  for (int co = 0; co < CIN; ++co) {
    double v = part[(size_t)co * NPIX + pp] + part1[(size_t)co * NPIX + pp] +
               (double)rpn_b[co];
    v = v > 0.0 ? v : 0.0;
#pragma unroll
    for (int a = 0; a < 9; ++a) accC[a] += (double)cls_w[a * CIN + co] * v;
#pragma unroll
    for (int c = 0; c < 36; ++c) accB[c] += (double)box_w[c * CIN + co] * v;
  }
  if (!act) return;
  int y = p / 50, x = p - y * 50;
  double sx = 16.0 * (double)x, sy = 16.0 * (double)y;
  const double scs[3] = {128.0, 256.0, 512.0};
  const double ars[3] = {0.5, 1.0, 2.0};
#pragma unroll
  for (int a = 0; a < 9; ++a) {
    double ar = ars[a / 3], sc = scs[a - (a / 3) * 3];
    double hr = sqrt(ar), wr = 1.0 / hr;
    double wv = wr * sc, hv = hr * sc;
    // jnp.round == round-half-even == rint under default rounding mode
    double bx0 = rint(-wv * 0.5), by0 = rint(-hv * 0.5);
    double bx1 = rint(wv * 0.5), by1 = rint(hv * 0.5);
    double a0 = sx + bx0, a1 = sy + by0, a2 = sx + bx1, a3 = sy + by1;
    double wA = a2 - a0, hA = a3 - a1;
    double cx = a0 + 0.5 * wA, cy = a1 + 0.5 * hA;
    double dx = accB[a * 4 + 0] + (double)box_b[a * 4 + 0];
    double dy = accB[a * 4 + 1] + (double)box_b[a * 4 + 1];
    double dw = accB[a * 4 + 2] + (double)box_b[a * 4 + 2];
    double dh = accB[a * 4 + 3] + (double)box_b[a * 4 + 3];
    double pcx = wA * dx + cx, pcy = hA * dy + cy;
    double pw = exp(dw) * wA, ph = exp(dh) * hA;
    double b0 = pcx - 0.5 * pw, b1 = pcy - 0.5 * ph;
    double b2 = pcx + 0.5 * pw, b3 = pcy + 0.5 * ph;
    b0 = fmin(fmax(b0, 0.0), 800.0);
    b1 = fmin(fmax(b1, 0.0), 800.0);
    b2 = fmin(fmax(b2, 0.0), 800.0);
    b3 = fmin(fmax(b3, 0.0), 800.0);
    int idx = p * 9 + a;
    boxesAll[(size_t)idx * 4 + 0] = b0;
    boxesAll[(size_t)idx * 4 + 1] = b1;
    boxesAll[(size_t)idx * 4 + 2] = b2;
    boxesAll[(size_t)idx * 4 + 3] = b3;
    double L = accC[a] + (double)cls_b[a];
    logits[idx] = L;
    out_cls[idx] = (float)L;
  }
}

// ---------------- exact stable descending rank (== jax.lax.top_k order) ---
__global__ __launch_bounds__(256) void rank_count(const double* __restrict__ logits,
                                                  int* __restrict__ ranks) {
  __shared__ double Ls[2048];
  int i = blockIdx.x * 256 + threadIdx.x;
  int j0 = blockIdx.y * 2048;
  int jn = NBOX - j0;
  if (jn > 2048) jn = 2048;
  for (int t = threadIdx.x; t < jn; t += 256) Ls[t] = logits[j0 + t];
  __syncthreads();
  if (i >= NBOX) return;
  double Li = logits[i];
  int cnt = 0;
  for (int t = 0; t < jn; ++t) {
    double Lj = Ls[t];
    int j = j0 + t;
    cnt += (Lj > Li || (Lj == Li && j < i)) ? 1 : 0;
  }
  atomicAdd(&ranks[i], cnt);
}

__global__ __launch_bounds__(256) void scatter_topk(const double* __restrict__ logits,
                                                    const double* __restrict__ boxesAll,
                                                    const int* __restrict__ ranks,
                                                    double* __restrict__ sLog,
                                                    double* __restrict__ sBox) {
  int i = blockIdx.x * 256 + threadIdx.x;
  if (i >= NBOX) return;
  int r = ranks[i];
  if (r < TOPK1) {
    sLog[r] = logits[i];
    sBox[(size_t)r * 4 + 0] = boxesAll[(size_t)i * 4 + 0];
    sBox[(size_t)r * 4 + 1] = boxesAll[(size_t)i * 4 + 1];
    sBox[(size_t)r * 4 + 2] = boxesAll[(size_t)i * 4 + 2];
    sBox[(size_t)r * 4 + 3] = boxesAll[(size_t)i * 4 + 3];
  }
}

// ---------------- pairwise IoU suppression bitmask (upper triangle) --------
// grid (157 i-tiles, 40 word-tiles), block 256 = 64 i x 4 words.
__global__ __launch_bounds__(256) void iou_mask(const double* __restrict__ sb,
                                                ull* __restrict__ mask) {
  const int it = blockIdx.x;
  const int wt = blockIdx.y;
  if (wt * 4 + 3 < it) return;  // block only needed for words >= i/64
  __shared__ double ib[64][4];
  __shared__ double jb[256][4];
  const int tid = threadIdx.x;
  {
    int ii = it * 64 + (tid >> 2);
    int d = tid & 3;
    ib[tid >> 2][d] = (ii < TOPK1) ? sb[(size_t)ii * 4 + d] : 0.0;
  }
  for (int t = tid; t < 1024; t += 256) {
    int jj = wt * 256 + (t >> 2);
    jb[t >> 2][t & 3] = (jj < TOPK1) ? sb[(size_t)jj * 4 + (t & 3)] : 0.0;
  }
  __syncthreads();
  const int il = tid & 63, wl = tid >> 6;
  const int i = it * 64 + il;
  const int word = wt * 4 + wl;
  if (i >= TOPK1 || word >= WORDS || word < (i >> 6)) return;
  const double x0 = ib[il][0], y0 = ib[il][1], x1 = ib[il][2], y1 = ib[il][3];
  const double areai = (x1 - x0) * (y1 - y0);
  ull bits = 0;
  const int jbase = word * 64;
  for (int b = 0; b < 64; ++b) {
    int j = jbase + b;
    if (j <= i || j >= TOPK1) continue;
    int jl = wl * 64 + b;
    double u0 = jb[jl][0], u1 = jb[jl][1], u2 = jb[jl][2], u3 = jb[jl][3];
    double xl = fmax(x0, u0), yt = fmax(y0, u1);
    double xr = fmin(x1, u2), yb = fmin(y1, u3);
    double iw = xr - xl, ih = yb - yt;
    iw = iw > 0.0 ? iw : 0.0;
    ih = ih > 0.0 ? ih : 0.0;
    double inter = iw * ih;
    double aj = (u2 - u0) * (u3 - u1);
    double un = areai + aj - inter;
    // reference: inter/un > 0.7 (0/0 -> NaN -> false). Multiply form matches.
    if (inter > 0.7 * un) bits |= 1ull << b;
  }
  mask[(size_t)i * WORDS + word] = bits;
}

// ---------------- sequential greedy-NMS scan, deferred column-OR -----------
// 256 threads. remv word g is computed on demand at group g as the OR of
// column g over all kept-so-far rows (klist in LDS). One batched load window
// per group (8-deep) instead of per-4-kept-rows; next group's diagonal word
// (mrow) prefetched one group ahead. Resolution stays serial on wave 0.
__global__ __launch_bounds__(256) void nms_scan(const ull* __restrict__ mask,
                                               ull* __restrict__ keepwords) {
  __shared__ int klist[TOPK1];        // kept box indices, append-only
  __shared__ volatile int kcLds;      // kept count
  __shared__ ull remvParts[4];
  const int tid = threadIdx.x;
  const int lane = tid & 63;
  const int wave = tid >> 6;
  if (tid == 0) kcLds = 0;
  __syncthreads();
  ull mrow_next = 0;
  if (wave == 0) mrow_next = mask[(size_t)lane * WORDS];  // group 0 diagonal
  for (int g = 0; g < WORDS; ++g) {
    int kc = kcLds;
    ull mrow_cur = 0;
    if (wave == 0) {
      mrow_cur = mrow_next;
      int gn = g + 1;
      if (gn < WORDS) {
        int iN = gn * 64 + lane;
        mrow_next = (iN < TOPK1) ? mask[(size_t)iN * WORDS + gn] : 0ull;
      }
    }
    // ---- phase A: acc = OR over kept rows' word g (8-deep batched) ----
    ull acc = 0;
    int t = tid;
    for (; t + 1792 < kc; t += 2048) {
      ull v0 = mask[(size_t)klist[t       ] * WORDS + g];
      ull v1 = mask[(size_t)klist[t +  256] * WORDS + g];
      ull v2 = mask[(size_t)klist[t +  512] * WORDS + g];
      ull v3 = mask[(size_t)klist[t +  768] * WORDS + g];
      ull v4 = mask[(size_t)klist[t + 1024] * WORDS + g];
      ull v5 = mask[(size_t)klist[t + 1280] * WORDS + g];
      ull v6 = mask[(size_t)klist[t + 1536] * WORDS + g];
      ull v7 = mask[(size_t)klist[t + 1792] * WORDS + g];
      acc |= ((v0 | v1) | (v2 | v3)) | ((v4 | v5) | (v6 | v7));
    }
    for (; t < kc; t += 256) acc |= mask[(size_t)klist[t] * WORDS + g];
#pragma unroll
    for (int off = 32; off > 0; off >>= 1) acc |= __shfl_xor(acc, off);
    if (lane == 0) remvParts[wave] = acc;
    __syncthreads();
    // ---- phase B: wave 0 resolves intra-group suppression serially ----
    if (wave == 0) {
      ull cur = remvParts[0] | remvParts[1] | remvParts[2] | remvParts[3];
      ull rem = ~cur;
      if (g == WORDS - 1) rem &= 0xFFFFull;  // only 16 boxes in last group
      const ull mrow = mrow_cur;
      while (rem) {
        int b = __ffsll((long long)rem) - 1;
        ull m = __shfl(mrow, b);  // row (g*64+b)'s own word (bits > b only)
        cur |= m;
        ull above = (b == 63) ? 0ull : ~((2ull << b) - 1ull);
        rem = (~cur) & rem & above;
      }
      ull validm = (g == WORDS - 1) ? 0xFFFFull : ~0ull;
      ull kb = (~cur) & validm;
      if (lane == 0) keepwords[g] = kb;
      int kc0 = kcLds;
      if ((kb >> lane) & 1ull) {
        ull below = lane ? (kb & ((1ull << lane) - 1ull)) : 0ull;
        klist[kc0 + __popcll(below)] = g * 64 + lane;
      }
      if (lane == 0) kcLds = kc0 + __popcll(kb);
    }
    __syncthreads();
  }
}

// ---------------- compact kept boxes, sigmoid scores, write output ---------
__global__ __launch_bounds__(256) void finalize_kernel(const ull* __restrict__ keepwords,
                                                       const double* __restrict__ sBox,
                                                       const double* __restrict__ sLog,
                                                       float* __restrict__ out) {
  __shared__ int pref[WORDS];
  int t = threadIdx.x;
  if (t == 0) {
    int s = 0;
    for (int w = 0; w < WORDS; ++w) {
      pref[w] = s;
      s += __popcll(keepwords[w]);
    }
  }
  __syncthreads();
  if (t < WORDS) {
    ull kb = keepwords[t];
    int base = pref[t];
    while (kb) {
      int b = __ffsll((long long)kb) - 1;
      kb &= kb - 1;
      if (base < TOPK2) {
        int i = t * 64 + b;
        out[base * 4 + 0] = (float)sBox[(size_t)i * 4 + 0];
        out[base * 4 + 1] = (float)sBox[(size_t)i * 4 + 1];
        out[base * 4 + 2] = (float)sBox[(size_t)i * 4 + 2];
        out[base * 4 + 3] = (float)sBox[(size_t)i * 4 + 3];
        double L = sLog[i];
        out[TOPK2 * 4 + base] = (float)(1.0 / (1.0 + exp(-L)));
      }
      ++base;
    }
  }
}

// ---------------------------------------------------------------------------
extern "C" void kernel_launch(void* const* d_in, const int* in_sizes, int n_in,
                              void* d_out, int out_size, void* d_ws, size_t ws_size,
                              hipStream_t stream) {
  // inputs: 0 image(unused) 1 feat 2 rpn_w 3 rpn_b 4 cls_w 5 cls_b 6 box_w 7 box_b
  const float* feat  = (const float*)d_in[1];
  const float* rpn_w = (const float*)d_in[2];
  const float* rpn_b = (const float*)d_in[3];
  const float* cls_w = (const float*)d_in[4];
  const float* cls_b = (const float*)d_in[5];
  const float* box_w = (const float*)d_in[6];
  const float* box_b = (const float*)d_in[7];
  float* out = (float*)d_out;

  // workspace layout (bytes, all 16B aligned); total ~34.44 MB
  char* ws = (char*)d_ws;
  double* part     = (double*)(ws);                 // 2*512*2500*8 = 20,480,000
  double* logits   = (double*)(ws + 20480000);      // 22500*8     =    180,000
  double* boxesAll = (double*)(ws + 20660000);      // 22500*4*8   =    720,000
  int*    ranks    = (int*)   (ws + 21380000);      // 22500*4     =     90,000
  double* sBox     = (double*)(ws + 21470000);      // 10000*4*8   =    320,000
  double* sLog     = (double*)(ws + 21790000);      // 10000*8     =     80,000
  ull*    mask     = (ull*)   (ws + 21870000);      // 10000*157*8 = 12,560,000
  ull*    keepw    = (ull*)   (ws + 34430000);      // 157*8       =      1,256

  hipMemsetAsync(d_out, 0, (TOPK2 * 4 + TOPK2) * sizeof(float), stream);
  hipMemsetAsync(ranks, 0, NBOX * sizeof(int), stream);

  conv_gemm<<<dim3(40, 8, 2), 256, 0, stream>>>(feat, rpn_w, part);
  heads_kernel<<<10, 256, 0, stream>>>(part, rpn_b, cls_w, cls_b, box_w, box_b,
                                       logits, boxesAll, out + TOPK2 * 5);
  rank_count<<<dim3(88, 11), 256, 0, stream>>>(logits, ranks);
  scatter_topk<<<88, 256, 0, stream>>>(logits, boxesAll, ranks, sLog, sBox);
  iou_mask<<<dim3(WORDS, 40), 256, 0, stream>>>(sBox, mask);
  nms_scan<<<1, 256, 0, stream>>>(mask, keepw);
  finalize_kernel<<<1, 256, 0, stream>>>(keepw, sBox, sLog, out);
}

// Round 4
// 1478.812 us; speedup vs baseline: 1.1413x; 1.1028x over previous
//
#include <hip/hip_runtime.h>
#include <cstdint>
#include <cstddef>

// ---------------------------------------------------------------------------
// RPN pipeline, fp64-accurate (ordering-critical: top-k rank + NMS decisions).
// fp32 inputs; all reductions accumulate in double (fp32*fp32 exact in f64).
// ---------------------------------------------------------------------------

typedef unsigned long long ull;

#define NANCH 9
#define NPIX  2500      // 50*50
#define CIN   512
#define COUT  512
#define KTOT  4608      // 512*9
#define KSEG  2304      // KTOT/2
#define NBOX  22500     // 2500*9
#define TOPK1 10000
#define TOPK2 2000
#define WORDS 157       // ceil(10000/64)

// ---------------- conv 3x3 as implicit-im2col GEMM, fp64 accum -------------
// grid (40 p-tiles, 8 co-tiles, 2 k-segments), block 256.
// Writes raw partial sums part[z][co][p] (bias+relu applied in heads).
__global__ __launch_bounds__(256) void conv_gemm(const float* __restrict__ feat,
                                                 const float* __restrict__ w,
                                                 double* __restrict__ part) {
  const int p0  = blockIdx.x * 64;
  const int co0 = blockIdx.y * 64;
  const int z   = blockIdx.z;
  const int kseg0 = z * KSEG;
  __shared__ float As[16][68];   // [k][co], padded to 68 (16B-aligned rows)
  __shared__ float Bs[16][68];   // [k][p]
  const int tid = threadIdx.x;
  const int tx = tid & 15, ty = tid >> 4;       // compute: p dir, co dir
  const int coA = tid >> 2, kA = (tid & 3) * 4; // A staging
  const int plB = tid & 63, kB0 = tid >> 6;     // B staging
  const int pB = p0 + plB;
  const int py = pB / 50, px = pB - py * 50;
  double acc[4][4];
#pragma unroll
  for (int i = 0; i < 4; ++i)
#pragma unroll
    for (int j = 0; j < 4; ++j) acc[i][j] = 0.0;

  for (int k0 = 0; k0 < KSEG; k0 += 16) {
    // A: weights are already [co][k] contiguous (OIHW with k = ci*9+ky*3+kx)
    float4 a4 = *(const float4*)(w + (size_t)(co0 + coA) * KTOT + (kseg0 + k0 + kA));
    // B: on-the-fly im2col (exact copy of fp32 feat values, zero padding)
    float bv[4];
#pragma unroll
    for (int jj = 0; jj < 4; ++jj) {
      int k = kseg0 + k0 + kB0 + 4 * jj;
      int ci = k / 9;
      int r  = k - ci * 9;
      int ky = r / 3;
      int kx = r - ky * 3;
      int yy = py + ky - 1, xx = px + kx - 1;
      float v = 0.0f;
      if (pB < NPIX && yy >= 0 && yy < 50 && xx >= 0 && xx < 50)
        v = feat[ci * NPIX + yy * 50 + xx];
      bv[jj] = v;
    }
    __syncthreads();
    As[kA + 0][coA] = a4.x;
    As[kA + 1][coA] = a4.y;
    As[kA + 2][coA] = a4.z;
    As[kA + 3][coA] = a4.w;
#pragma unroll
    for (int jj = 0; jj < 4; ++jj) Bs[kB0 + 4 * jj][plB] = bv[jj];
    __syncthreads();
#pragma unroll
    for (int k = 0; k < 16; ++k) {
      float4 av = *(const float4*)&As[k][ty * 4];
      float4 b4 = *(const float4*)&Bs[k][tx * 4];
      double ad[4] = {(double)av.x, (double)av.y, (double)av.z, (double)av.w};
      double bd[4] = {(double)b4.x, (double)b4.y, (double)b4.z, (double)b4.w};
#pragma unroll
      for (int i = 0; i < 4; ++i)
#pragma unroll
        for (int j = 0; j < 4; ++j) acc[i][j] += ad[i] * bd[j];
    }
  }
#pragma unroll
  for (int i = 0; i < 4; ++i) {
    int co = co0 + ty * 4 + i;
#pragma unroll
    for (int j = 0; j < 4; ++j) {
      int p = p0 + tx * 4 + j;
      if (p < NPIX)
        part[(size_t)z * COUT * NPIX + (size_t)co * NPIX + p] = acc[i][j];
    }
  }
}

// ---------------- heads: relu(conv)+bias, cls+box 1x1 convs, decode --------
__global__ __launch_bounds__(256) void heads_kernel(
    const double* __restrict__ part, const float* __restrict__ rpn_b,
    const float* __restrict__ cls_w, const float* __restrict__ cls_b,
    const float* __restrict__ box_w, const float* __restrict__ box_b,
    double* __restrict__ logits, double* __restrict__ boxesAll,
    float* __restrict__ out_cls) {
  int p = blockIdx.x * blockDim.x + threadIdx.x;
  bool act = p < NPIX;
  int pp = act ? p : 0;
  double accC[9];
  double accB[36];
#pragma unroll
  for (int a = 0; a < 9; ++a) accC[a] = 0.0;
#pragma unroll
  for (int c = 0; c < 36; ++c) accB[c] = 0.0;
  const double* part1 = part + (size_t)COUT * NPIX;
  for (int co = 0; co < CIN; ++co) {
    double v = part[(size_t)co * NPIX + pp] + part1[(size_t)co * NPIX + pp] +
               (double)rpn_b[co];
    v = v > 0.0 ? v : 0.0;
#pragma unroll
    for (int a = 0; a < 9; ++a) accC[a] += (double)cls_w[a * CIN + co] * v;
#pragma unroll
    for (int c = 0; c < 36; ++c) accB[c] += (double)box_w[c * CIN + co] * v;
  }
  if (!act) return;
  int y = p / 50, x = p - y * 50;
  double sx = 16.0 * (double)x, sy = 16.0 * (double)y;
  const double scs[3] = {128.0, 256.0, 512.0};
  const double ars[3] = {0.5, 1.0, 2.0};
#pragma unroll
  for (int a = 0; a < 9; ++a) {
    double ar = ars[a / 3], sc = scs[a - (a / 3) * 3];
    double hr = sqrt(ar), wr = 1.0 / hr;
    double wv = wr * sc, hv = hr * sc;
    // jnp.round == round-half-even == rint under default rounding mode
    double bx0 = rint(-wv * 0.5), by0 = rint(-hv * 0.5);
    double bx1 = rint(wv * 0.5), by1 = rint(hv * 0.5);
    double a0 = sx + bx0, a1 = sy + by0, a2 = sx + bx1, a3 = sy + by1;
    double wA = a2 - a0, hA = a3 - a1;
    double cx = a0 + 0.5 * wA, cy = a1 + 0.5 * hA;
    double dx = accB[a * 4 + 0] + (double)box_b[a * 4 + 0];
    double dy = accB[a * 4 + 1] + (double)box_b[a * 4 + 1];
    double dw = accB[a * 4 + 2] + (double)box_b[a * 4 + 2];
    double dh = accB[a * 4 + 3] + (double)box_b[a * 4 + 3];
    double pcx = wA * dx + cx, pcy = hA * dy + cy;
    double pw = exp(dw) * wA, ph = exp(dh) * hA;
    double b0 = pcx - 0.5 * pw, b1 = pcy - 0.5 * ph;
    double b2 = pcx + 0.5 * pw, b3 = pcy + 0.5 * ph;
    b0 = fmin(fmax(b0, 0.0), 800.0);
    b1 = fmin(fmax(b1, 0.0), 800.0);
    b2 = fmin(fmax(b2, 0.0), 800.0);
    b3 = fmin(fmax(b3, 0.0), 800.0);
    int idx = p * 9 + a;
    boxesAll[(size_t)idx * 4 + 0] = b0;
    boxesAll[(size_t)idx * 4 + 1] = b1;
    boxesAll[(size_t)idx * 4 + 2] = b2;
    boxesAll[(size_t)idx * 4 + 3] = b3;
    double L = accC[a] + (double)cls_b[a];
    logits[idx] = L;
    out_cls[idx] = (float)L;
  }
}

// ---------------- exact stable descending rank (== jax.lax.top_k order) ---
__global__ __launch_bounds__(256) void rank_count(const double* __restrict__ logits,
                                                  int* __restrict__ ranks) {
  __shared__ double Ls[2048];
  int i = blockIdx.x * 256 + threadIdx.x;
  int j0 = blockIdx.y * 2048;
  int jn = NBOX - j0;
  if (jn > 2048) jn = 2048;
  for (int t = threadIdx.x; t < jn; t += 256) Ls[t] = logits[j0 + t];
  __syncthreads();
  if (i >= NBOX) return;
  double Li = logits[i];
  int cnt = 0;
  for (int t = 0; t < jn; ++t) {
    double Lj = Ls[t];
    int j = j0 + t;
    cnt += (Lj > Li || (Lj == Li && j < i)) ? 1 : 0;
  }
  atomicAdd(&ranks[i], cnt);
}

__global__ __launch_bounds__(256) void scatter_topk(const double* __restrict__ logits,
                                                    const double* __restrict__ boxesAll,
                                                    const int* __restrict__ ranks,
                                                    double* __restrict__ sLog,
                                                    double* __restrict__ sBox) {
  int i = blockIdx.x * 256 + threadIdx.x;
  if (i >= NBOX) return;
  int r = ranks[i];
  if (r < TOPK1) {
    sLog[r] = logits[i];
    sBox[(size_t)r * 4 + 0] = boxesAll[(size_t)i * 4 + 0];
    sBox[(size_t)r * 4 + 1] = boxesAll[(size_t)i * 4 + 1];
    sBox[(size_t)r * 4 + 2] = boxesAll[(size_t)i * 4 + 2];
    sBox[(size_t)r * 4 + 3] = boxesAll[(size_t)i * 4 + 3];
  }
}

// ---------------- pairwise IoU suppression bitmask (upper triangle) --------
// grid (157 i-tiles, 40 word-tiles), block 256 = 64 i x 4 words.
__global__ __launch_bounds__(256) void iou_mask(const double* __restrict__ sb,
                                                ull* __restrict__ mask) {
  const int it = blockIdx.x;
  const int wt = blockIdx.y;
  if (wt * 4 + 3 < it) return;  // block only needed for words >= i/64
  __shared__ double ib[64][4];
  __shared__ double jb[256][4];
  const int tid = threadIdx.x;
  {
    int ii = it * 64 + (tid >> 2);
    int d = tid & 3;
    ib[tid >> 2][d] = (ii < TOPK1) ? sb[(size_t)ii * 4 + d] : 0.0;
  }
  for (int t = tid; t < 1024; t += 256) {
    int jj = wt * 256 + (t >> 2);
    jb[t >> 2][t & 3] = (jj < TOPK1) ? sb[(size_t)jj * 4 + (t & 3)] : 0.0;
  }
  __syncthreads();
  const int il = tid & 63, wl = tid >> 6;
  const int i = it * 64 + il;
  const int word = wt * 4 + wl;
  if (i >= TOPK1 || word >= WORDS || word < (i >> 6)) return;
  const double x0 = ib[il][0], y0 = ib[il][1], x1 = ib[il][2], y1 = ib[il][3];
  const double areai = (x1 - x0) * (y1 - y0);
  ull bits = 0;
  const int jbase = word * 64;
  for (int b = 0; b < 64; ++b) {
    int j = jbase + b;
    if (j <= i || j >= TOPK1) continue;
    int jl = wl * 64 + b;
    double u0 = jb[jl][0], u1 = jb[jl][1], u2 = jb[jl][2], u3 = jb[jl][3];
    double xl = fmax(x0, u0), yt = fmax(y0, u1);
    double xr = fmin(x1, u2), yb = fmin(y1, u3);
    double iw = xr - xl, ih = yb - yt;
    iw = iw > 0.0 ? iw : 0.0;
    ih = ih > 0.0 ? ih : 0.0;
    double inter = iw * ih;
    double aj = (u2 - u0) * (u3 - u1);
    double un = areai + aj - inter;
    // reference: inter/un > 0.7 (0/0 -> NaN -> false). Multiply form matches.
    if (inter > 0.7 * un) bits |= 1ull << b;
  }
  mask[(size_t)i * WORDS + word] = bits;
}

// ---- DPP 64-lane OR reduce (VALU pipe; canonical GCN3 row_shr/bcast seq) --
__device__ __forceinline__ unsigned int wave_or_u32(unsigned int v) {
  int x = (int)v;
  x |= __builtin_amdgcn_update_dpp(0, x, 0x111, 0xF, 0xF, false); // row_shr:1
  x |= __builtin_amdgcn_update_dpp(0, x, 0x112, 0xF, 0xF, false); // row_shr:2
  x |= __builtin_amdgcn_update_dpp(0, x, 0x114, 0xF, 0xF, false); // row_shr:4
  x |= __builtin_amdgcn_update_dpp(0, x, 0x118, 0xF, 0xF, false); // row_shr:8
  x |= __builtin_amdgcn_update_dpp(0, x, 0x142, 0xA, 0xF, false); // bcast15
  x |= __builtin_amdgcn_update_dpp(0, x, 0x143, 0xC, 0xF, false); // bcast31
  return (unsigned int)__builtin_amdgcn_readlane(x, 63);
}
__device__ __forceinline__ ull wave_or_u64(ull v) {
  unsigned int lo = wave_or_u32((unsigned int)v);
  unsigned int hi = wave_or_u32((unsigned int)(v >> 32));
  return ((ull)hi << 32) | lo;
}

// ---------------- sequential greedy-NMS scan, pipelined column-OR ----------
// remv word g = OR of column g over kept rows. Pipelined: loads for group g+1
// (column over klist, speculative group-g rows' word g+1, diagonal g+1) are
// ISSUED at iteration g and consumed after phase B — hidden behind resolve.
// Cross-lane ops use DPP + readlane (VALU pipe), not LDS shuffles.
__global__ __launch_bounds__(256) void nms_scan(const ull* __restrict__ mask,
                                                ull* __restrict__ keepwords) {
  __shared__ int klist[TOPK1];     // kept box indices, append-only
  __shared__ ull remvAcc[6];       // [0..3] wave column partials, [4] spec
  __shared__ ull kbLds;
  __shared__ int kcLds;
  const int tid = threadIdx.x;
  const int lane = tid & 63;
  const int wave = tid >> 6;
  if (tid < 6) remvAcc[tid] = 0;
  if (tid == 0) { kcLds = 0; kbLds = 0; }
  ull mrow = 0;
  if (wave == 0) mrow = mask[(size_t)lane * WORDS];  // group 0 diagonal
  int kc = 0;
  __syncthreads();

  for (int g = 0; g < WORDS; ++g) {
    const int gn = g + 1;
    const bool hasNext = (gn < WORDS);
    // ---- STEP 1: issue loads for group gn (consumed at step 4) ----------
    ull cv[16];
    int okm = 0;
    ull accExtra = 0;
    ull spec = 0, mnext = 0;
    if (hasNext) {
#pragma unroll
      for (int q = 0; q < 16; ++q) {
        int t = tid + q * 256;
        bool ok = t < kc;
        int r = ok ? klist[t] : 0;           // clamp to row 0, mask value later
        cv[q] = mask[(size_t)r * WORDS + gn];
        okm |= ok ? (1 << q) : 0;
      }
      // rare overflow path (kc > 4096): serial, correct
      for (int t = tid + 4096; t < kc; t += 256)
        accExtra |= mask[(size_t)klist[t] * WORDS + gn];
      if (wave == 1) {  // speculative: word gn of all group-g rows
        int r = g * 64 + lane;
        spec = (r < TOPK1) ? mask[(size_t)r * WORDS + gn] : 0;
      }
      if (wave == 0) {  // diagonal prefetch for group gn
        int r = gn * 64 + lane;
        mnext = (r < TOPK1) ? mask[(size_t)r * WORDS + gn] : 0;
      }
    }
    // ---- STEP 2: wave 0 resolves group g (scalar-domain serial loop) ----
    if (wave == 0) {
      ull cur = remvAcc[0] | remvAcc[1] | remvAcc[2] | remvAcc[3] | remvAcc[4];
      unsigned int clo = __builtin_amdgcn_readfirstlane((unsigned int)cur);
      unsigned int chi = __builtin_amdgcn_readfirstlane((unsigned int)(cur >> 32));
      cur = ((ull)chi << 32) | clo;
      const unsigned int ml = (unsigned int)mrow;
      const unsigned int mh = (unsigned int)(mrow >> 32);
      const ull validm = (g == WORDS - 1) ? 0xFFFFull : ~0ull;
      ull rem = (~cur) & validm;
      while (rem) {
        int b = __ffsll((long long)rem) - 1;
        b = __builtin_amdgcn_readfirstlane(b);
        ull m = ((ull)(unsigned int)__builtin_amdgcn_readlane((int)mh, b) << 32) |
                (unsigned int)__builtin_amdgcn_readlane((int)ml, b);
        cur |= m;
        ull above = (b == 63) ? 0ull : (~0ull << (b + 1));
        rem = (~cur) & rem & above;
      }
      ull kb = (~cur) & validm;
      if (lane == 0) { keepwords[g] = kb; kbLds = kb; }
      if ((kb >> lane) & 1ull) {
        ull below = lane ? (kb & ((1ull << lane) - 1ull)) : 0ull;
        klist[kc + __popcll(below)] = g * 64 + lane;
      }
      if (lane == 0) kcLds = kc + __popcll(kb);
    }
    __syncthreads();  // kb visible; step-1 loads drained (vmcnt0 at barrier)
    // ---- STEP 4: fold loads into remv accumulators for group gn ----------
    if (hasNext) {
      ull acc = accExtra;
#pragma unroll
      for (int q = 0; q < 16; ++q) acc |= ((okm >> q) & 1) ? cv[q] : 0;
      ull w = wave_or_u64(acc);
      if (lane == 0) remvAcc[wave] = w;
      if (wave == 1) {
        ull kbv = kbLds;
        ull sv = ((kbv >> lane) & 1ull) ? spec : 0;
        ull s = wave_or_u64(sv);
        if (lane == 0) remvAcc[4] = s;
      }
    }
    __syncthreads();  // remvAcc/klist/kc visible for next iteration
    kc = kcLds;
    if (wave == 0) mrow = mnext;
  }
}

// ---------------- compact kept boxes, sigmoid scores, write output ---------
__global__ __launch_bounds__(256) void finalize_kernel(const ull* __restrict__ keepwords,
                                                       const double* __restrict__ sBox,
                                                       const double* __restrict__ sLog,
                                                       float* __restrict__ out) {
  __shared__ int pref[WORDS];
  int t = threadIdx.x;
  if (t == 0) {
    int s = 0;
    for (int w = 0; w < WORDS; ++w) {
      pref[w] = s;
      s += __popcll(keepwords[w]);
    }
  }
  __syncthreads();
  if (t < WORDS) {
    ull kb = keepwords[t];
    int base = pref[t];
    while (kb) {
      int b = __ffsll((long long)kb) - 1;
      kb &= kb - 1;
      if (base < TOPK2) {
        int i = t * 64 + b;
        out[base * 4 + 0] = (float)sBox[(size_t)i * 4 + 0];
        out[base * 4 + 1] = (float)sBox[(size_t)i * 4 + 1];
        out[base * 4 + 2] = (float)sBox[(size_t)i * 4 + 2];
        out[base * 4 + 3] = (float)sBox[(size_t)i * 4 + 3];
        double L = sLog[i];
        out[TOPK2 * 4 + base] = (float)(1.0 / (1.0 + exp(-L)));
      }
      ++base;
    }
  }
}

// ---------------------------------------------------------------------------
extern "C" void kernel_launch(void* const* d_in, const int* in_sizes, int n_in,
                              void* d_out, int out_size, void* d_ws, size_t ws_size,
                              hipStream_t stream) {
  // inputs: 0 image(unused) 1 feat 2 rpn_w 3 rpn_b 4 cls_w 5 cls_b 6 box_w 7 box_b
  const float* feat  = (const float*)d_in[1];
  const float* rpn_w = (const float*)d_in[2];
  const float* rpn_b = (const float*)d_in[3];
  const float* cls_w = (const float*)d_in[4];
  const float* cls_b = (const float*)d_in[5];
  const float* box_w = (const float*)d_in[6];
  const float* box_b = (const float*)d_in[7];
  float* out = (float*)d_out;

  // workspace layout (bytes, all 16B aligned); total ~34.44 MB
  char* ws = (char*)d_ws;
  double* part     = (double*)(ws);                 // 2*512*2500*8 = 20,480,000
  double* logits   = (double*)(ws + 20480000);      // 22500*8     =    180,000
  double* boxesAll = (double*)(ws + 20660000);      // 22500*4*8   =    720,000
  int*    ranks    = (int*)   (ws + 21380000);      // 22500*4     =     90,000
  double* sBox     = (double*)(ws + 21470000);      // 10000*4*8   =    320,000
  double* sLog     = (double*)(ws + 21790000);      // 10000*8     =     80,000
  ull*    mask     = (ull*)   (ws + 21870000);      // 10000*157*8 = 12,560,000
  ull*    keepw    = (ull*)   (ws + 34430000);      // 157*8       =      1,256

  hipMemsetAsync(d_out, 0, (TOPK2 * 4 + TOPK2) * sizeof(float), stream);
  hipMemsetAsync(ranks, 0, NBOX * sizeof(int), stream);

  conv_gemm<<<dim3(40, 8, 2), 256, 0, stream>>>(feat, rpn_w, part);
  heads_kernel<<<10, 256, 0, stream>>>(part, rpn_b, cls_w, cls_b, box_w, box_b,
                                       logits, boxesAll, out + TOPK2 * 5);
  rank_count<<<dim3(88, 11), 256, 0, stream>>>(logits, ranks);
  scatter_topk<<<88, 256, 0, stream>>>(logits, boxesAll, ranks, sLog, sBox);
  iou_mask<<<dim3(WORDS, 40), 256, 0, stream>>>(sBox, mask);
  nms_scan<<<1, 256, 0, stream>>>(mask, keepw);
  finalize_kernel<<<1, 256, 0, stream>>>(keepw, sBox, sLog, out);
}

// Round 5
// 1212.100 us; speedup vs baseline: 1.3924x; 1.2200x over previous
//
#include <hip/hip_runtime.h>
#include <cstdint>
#include <cstddef>

// ---------------------------------------------------------------------------
// RPN pipeline, fp64-accurate (ordering-critical: top-k rank + NMS decisions).
// fp32 inputs; all reductions accumulate in double (fp32*fp32 exact in f64).
// ---------------------------------------------------------------------------

typedef unsigned long long ull;

#define NANCH 9
#define NPIX  2500      // 50*50
#define CIN   512
#define COUT  512
#define KTOT  4608      // 512*9
#define KSEG  2304      // KTOT/2
#define NBOX  22500     // 2500*9
#define TOPK1 10000
#define TOPK2 2000
#define WORDS 157       // ceil(10000/64)

// ---------------- conv 3x3 as implicit-im2col GEMM, fp64 accum -------------
// grid (40 p-tiles, 8 co-tiles, 2 k-segments), block 256.
// Writes raw partial sums part[z][co][p] (bias+relu applied in heads).
__global__ __launch_bounds__(256) void conv_gemm(const float* __restrict__ feat,
                                                 const float* __restrict__ w,
                                                 double* __restrict__ part) {
  const int p0  = blockIdx.x * 64;
  const int co0 = blockIdx.y * 64;
  const int z   = blockIdx.z;
  const int kseg0 = z * KSEG;
  __shared__ float As[16][68];   // [k][co], padded to 68 (16B-aligned rows)
  __shared__ float Bs[16][68];   // [k][p]
  const int tid = threadIdx.x;
  const int tx = tid & 15, ty = tid >> 4;       // compute: p dir, co dir
  const int coA = tid >> 2, kA = (tid & 3) * 4; // A staging
  const int plB = tid & 63, kB0 = tid >> 6;     // B staging
  const int pB = p0 + plB;
  const int py = pB / 50, px = pB - py * 50;
  double acc[4][4];
#pragma unroll
  for (int i = 0; i < 4; ++i)
#pragma unroll
    for (int j = 0; j < 4; ++j) acc[i][j] = 0.0;

  for (int k0 = 0; k0 < KSEG; k0 += 16) {
    // A: weights are already [co][k] contiguous (OIHW with k = ci*9+ky*3+kx)
    float4 a4 = *(const float4*)(w + (size_t)(co0 + coA) * KTOT + (kseg0 + k0 + kA));
    // B: on-the-fly im2col (exact copy of fp32 feat values, zero padding)
    float bv[4];
#pragma unroll
    for (int jj = 0; jj < 4; ++jj) {
      int k = kseg0 + k0 + kB0 + 4 * jj;
      int ci = k / 9;
      int r  = k - ci * 9;
      int ky = r / 3;
      int kx = r - ky * 3;
      int yy = py + ky - 1, xx = px + kx - 1;
      float v = 0.0f;
      if (pB < NPIX && yy >= 0 && yy < 50 && xx >= 0 && xx < 50)
        v = feat[ci * NPIX + yy * 50 + xx];
      bv[jj] = v;
    }
    __syncthreads();
    As[kA + 0][coA] = a4.x;
    As[kA + 1][coA] = a4.y;
    As[kA + 2][coA] = a4.z;
    As[kA + 3][coA] = a4.w;
#pragma unroll
    for (int jj = 0; jj < 4; ++jj) Bs[kB0 + 4 * jj][plB] = bv[jj];
    __syncthreads();
#pragma unroll
    for (int k = 0; k < 16; ++k) {
      float4 av = *(const float4*)&As[k][ty * 4];
      float4 b4 = *(const float4*)&Bs[k][tx * 4];
      double ad[4] = {(double)av.x, (double)av.y, (double)av.z, (double)av.w};
      double bd[4] = {(double)b4.x, (double)b4.y, (double)b4.z, (double)b4.w};
#pragma unroll
      for (int i = 0; i < 4; ++i)
#pragma unroll
        for (int j = 0; j < 4; ++j) acc[i][j] += ad[i] * bd[j];
    }
  }
#pragma unroll
  for (int i = 0; i < 4; ++i) {
    int co = co0 + ty * 4 + i;
#pragma unroll
    for (int j = 0; j < 4; ++j) {
      int p = p0 + tx * 4 + j;
      if (p < NPIX)
        part[(size_t)z * COUT * NPIX + (size_t)co * NPIX + p] = acc[i][j];
    }
  }
}

// ---------------- heads: relu(conv)+bias, cls+box 1x1 convs, decode --------
__global__ __launch_bounds__(256) void heads_kernel(
    const double* __restrict__ part, const float* __restrict__ rpn_b,
    const float* __restrict__ cls_w, const float* __restrict__ cls_b,
    const float* __restrict__ box_w, const float* __restrict__ box_b,
    double* __restrict__ logits, double* __restrict__ boxesAll,
    float* __restrict__ out_cls) {
  int p = blockIdx.x * blockDim.x + threadIdx.x;
  bool act = p < NPIX;
  int pp = act ? p : 0;
  double accC[9];
  double accB[36];
#pragma unroll
  for (int a = 0; a < 9; ++a) accC[a] = 0.0;
#pragma unroll
  for (int c = 0; c < 36; ++c) accB[c] = 0.0;
  const double* part1 = part + (size_t)COUT * NPIX;
  for (int co = 0; co < CIN; ++co) {
    double v = part[(size_t)co * NPIX + pp] + part1[(size_t)co * NPIX + pp] +
               (double)rpn_b[co];
    v = v > 0.0 ? v : 0.0;
#pragma unroll
    for (int a = 0; a < 9; ++a) accC[a] += (double)cls_w[a * CIN + co] * v;
#pragma unroll
    for (int c = 0; c < 36; ++c) accB[c] += (double)box_w[c * CIN + co] * v;
  }
  if (!act) return;
  int y = p / 50, x = p - y * 50;
  double sx = 16.0 * (double)x, sy = 16.0 * (double)y;
  const double scs[3] = {128.0, 256.0, 512.0};
  const double ars[3] = {0.5, 1.0, 2.0};
#pragma unroll
  for (int a = 0; a < 9; ++a) {
    double ar = ars[a / 3], sc = scs[a - (a / 3) * 3];
    double hr = sqrt(ar), wr = 1.0 / hr;
    double wv = wr * sc, hv = hr * sc;
    // jnp.round == round-half-even == rint under default rounding mode
    double bx0 = rint(-wv * 0.5), by0 = rint(-hv * 0.5);
    double bx1 = rint(wv * 0.5), by1 = rint(hv * 0.5);
    double a0 = sx + bx0, a1 = sy + by0, a2 = sx + bx1, a3 = sy + by1;
    double wA = a2 - a0, hA = a3 - a1;
    double cx = a0 + 0.5 * wA, cy = a1 + 0.5 * hA;
    double dx = accB[a * 4 + 0] + (double)box_b[a * 4 + 0];
    double dy = accB[a * 4 + 1] + (double)box_b[a * 4 + 1];
    double dw = accB[a * 4 + 2] + (double)box_b[a * 4 + 2];
    double dh = accB[a * 4 + 3] + (double)box_b[a * 4 + 3];
    double pcx = wA * dx + cx, pcy = hA * dy + cy;
    double pw = exp(dw) * wA, ph = exp(dh) * hA;
    double b0 = pcx - 0.5 * pw, b1 = pcy - 0.5 * ph;
    double b2 = pcx + 0.5 * pw, b3 = pcy + 0.5 * ph;
    b0 = fmin(fmax(b0, 0.0), 800.0);
    b1 = fmin(fmax(b1, 0.0), 800.0);
    b2 = fmin(fmax(b2, 0.0), 800.0);
    b3 = fmin(fmax(b3, 0.0), 800.0);
    int idx = p * 9 + a;
    boxesAll[(size_t)idx * 4 + 0] = b0;
    boxesAll[(size_t)idx * 4 + 1] = b1;
    boxesAll[(size_t)idx * 4 + 2] = b2;
    boxesAll[(size_t)idx * 4 + 3] = b3;
    double L = accC[a] + (double)cls_b[a];
    logits[idx] = L;
    out_cls[idx] = (float)L;
  }
}

// ---------------- exact stable descending rank (== jax.lax.top_k order) ---
__global__ __launch_bounds__(256) void rank_count(const double* __restrict__ logits,
                                                  int* __restrict__ ranks) {
  __shared__ double Ls[2048];
  int i = blockIdx.x * 256 + threadIdx.x;
  int j0 = blockIdx.y * 2048;
  int jn = NBOX - j0;
  if (jn > 2048) jn = 2048;
  for (int t = threadIdx.x; t < jn; t += 256) Ls[t] = logits[j0 + t];
  __syncthreads();
  if (i >= NBOX) return;
  double Li = logits[i];
  int cnt = 0;
  for (int t = 0; t < jn; ++t) {
    double Lj = Ls[t];
    int j = j0 + t;
    cnt += (Lj > Li || (Lj == Li && j < i)) ? 1 : 0;
  }
  atomicAdd(&ranks[i], cnt);
}

__global__ __launch_bounds__(256) void scatter_topk(const double* __restrict__ logits,
                                                    const double* __restrict__ boxesAll,
                                                    const int* __restrict__ ranks,
                                                    double* __restrict__ sLog,
                                                    double* __restrict__ sBox) {
  int i = blockIdx.x * 256 + threadIdx.x;
  if (i >= NBOX) return;
  int r = ranks[i];
  if (r < TOPK1) {
    sLog[r] = logits[i];
    sBox[(size_t)r * 4 + 0] = boxesAll[(size_t)i * 4 + 0];
    sBox[(size_t)r * 4 + 1] = boxesAll[(size_t)i * 4 + 1];
    sBox[(size_t)r * 4 + 2] = boxesAll[(size_t)i * 4 + 2];
    sBox[(size_t)r * 4 + 3] = boxesAll[(size_t)i * 4 + 3];
  }
}

// ---------------- pairwise IoU suppression bitmask (upper triangle) --------
// grid (157 i-tiles, 40 word-tiles), block 256 = 64 i x 4 words.
__global__ __launch_bounds__(256) void iou_mask(const double* __restrict__ sb,
                                                ull* __restrict__ mask) {
  const int it = blockIdx.x;
  const int wt = blockIdx.y;
  if (wt * 4 + 3 < it) return;  // block only needed for words >= i/64
  __shared__ double ib[64][4];
  __shared__ double jb[256][4];
  const int tid = threadIdx.x;
  {
    int ii = it * 64 + (tid >> 2);
    int d = tid & 3;
    ib[tid >> 2][d] = (ii < TOPK1) ? sb[(size_t)ii * 4 + d] : 0.0;
  }
  for (int t = tid; t < 1024; t += 256) {
    int jj = wt * 256 + (t >> 2);
    jb[t >> 2][t & 3] = (jj < TOPK1) ? sb[(size_t)jj * 4 + (t & 3)] : 0.0;
  }
  __syncthreads();
  const int il = tid & 63, wl = tid >> 6;
  const int i = it * 64 + il;
  const int word = wt * 4 + wl;
  if (i >= TOPK1 || word >= WORDS || word < (i >> 6)) return;
  const double x0 = ib[il][0], y0 = ib[il][1], x1 = ib[il][2], y1 = ib[il][3];
  const double areai = (x1 - x0) * (y1 - y0);
  ull bits = 0;
  const int jbase = word * 64;
  for (int b = 0; b < 64; ++b) {
    int j = jbase + b;
    if (j <= i || j >= TOPK1) continue;
    int jl = wl * 64 + b;
    double u0 = jb[jl][0], u1 = jb[jl][1], u2 = jb[jl][2], u3 = jb[jl][3];
    double xl = fmax(x0, u0), yt = fmax(y0, u1);
    double xr = fmin(x1, u2), yb = fmin(y1, u3);
    double iw = xr - xl, ih = yb - yt;
    iw = iw > 0.0 ? iw : 0.0;
    ih = ih > 0.0 ? ih : 0.0;
    double inter = iw * ih;
    double aj = (u2 - u0) * (u3 - u1);
    double un = areai + aj - inter;
    // reference: inter/un > 0.7 (0/0 -> NaN -> false). Multiply form matches.
    if (inter > 0.7 * un) bits |= 1ull << b;
  }
  mask[(size_t)i * WORDS + word] = bits;
}

// ---------------- tiled greedy-NMS scan, LDS-resident tile -----------------
// Tile = 8 groups (512 boxes). Per tile:
//   Phase A: stage 512x8 mask sub-block into LDS (coalesced 64B/row) and
//            compute base removal words = OR of column over previously-kept
//            rows (8 consecutive words/row -> coalesced full-line reads).
//   Phase B: 8 sequential group resolves touching ONLY LDS (diagonal +
//            forward-updates). Early exit once 2000 boxes kept (output only
//            needs the first TOPK2 kept; suppression flows forward only).
// keepwords is pre-zeroed by memset so skipped groups read as "none kept".
#define NTILE 8
#define TRS   10    // padded ull stride for tileRows (8 words + 2 pad)
#define KCAP  2112

__global__ __launch_bounds__(256) void nms_scan(const ull* __restrict__ mask,
                                                ull* __restrict__ keepwords) {
  __shared__ ull tileRows[512 * TRS];        // 40,960 B
  __shared__ int klist[KCAP];                // kept global indices (rank order)
  __shared__ ull remvPart[32][NTILE + 1];    // column-OR partials
  __shared__ unsigned int remv32[NTILE * 2]; // removal words (lo/hi pairs)
  __shared__ int newk[64];                   // this group's kept local rows
  __shared__ int kcLds, nkLds, doneLds;
  const int tid = threadIdx.x;
  const int lane = tid & 63;
  const int wave = tid >> 6;
  if (tid == 0) { kcLds = 0; nkLds = 0; doneLds = 0; }
  __syncthreads();

  for (int T = 0; T < (WORDS + NTILE - 1) / NTILE; ++T) {
    const int G0 = T * NTILE;
    const int TW = (WORDS - G0 < NTILE) ? (WORDS - G0) : NTILE;
    const int kc0 = kcLds;
    // ---- Phase A1: stage tile rows (512 x TW words) into LDS ----
#pragma unroll
    for (int pass = 0; pass < 8; ++pass) {
      int lr = pass * 64 + (tid >> 2);   // local row 0..511
      int w  = (tid & 3) * 2;            // word pair
      int gr = G0 * 64 + lr;             // global row
      ull v0 = 0, v1 = 0;
      if (gr < TOPK1) {
        const ull* row = mask + (size_t)gr * WORDS + G0;
        if (w < TW)     v0 = row[w];
        if (w + 1 < TW) v1 = row[w + 1];
      }
      tileRows[lr * TRS + w]     = v0;
      tileRows[lr * TRS + w + 1] = v1;
    }
    // ---- Phase A2: base removal words = OR over previously-kept rows ----
    {
      int w = tid & 7, stripe = tid >> 3;   // 32 stripes x 8 words
      ull acc = 0;
      if (w < TW) {
        int t = stripe;
        for (; t + 224 < kc0; t += 256) {
          ull a0 = mask[(size_t)klist[t      ] * WORDS + G0 + w];
          ull a1 = mask[(size_t)klist[t +  32] * WORDS + G0 + w];
          ull a2 = mask[(size_t)klist[t +  64] * WORDS + G0 + w];
          ull a3 = mask[(size_t)klist[t +  96] * WORDS + G0 + w];
          ull a4 = mask[(size_t)klist[t + 128] * WORDS + G0 + w];
          ull a5 = mask[(size_t)klist[t + 160] * WORDS + G0 + w];
          ull a6 = mask[(size_t)klist[t + 192] * WORDS + G0 + w];
          ull a7 = mask[(size_t)klist[t + 224] * WORDS + G0 + w];
          acc |= ((a0 | a1) | (a2 | a3)) | ((a4 | a5) | (a6 | a7));
        }
        for (; t < kc0; t += 32) acc |= mask[(size_t)klist[t] * WORDS + G0 + w];
      }
      remvPart[stripe][w] = acc;
    }
    __syncthreads();
    if (tid < NTILE) {
      ull r = 0;
#pragma unroll
      for (int s = 0; s < 32; ++s) r |= remvPart[s][tid];
      remv32[tid * 2]     = (unsigned int)r;
      remv32[tid * 2 + 1] = (unsigned int)(r >> 32);
    }
    __syncthreads();
    // ---- Phase B: sequential resolve of the tile's groups (LDS only) ----
    for (int gi = 0; gi < TW; ++gi) {
      const int g = G0 + gi;
      if (wave == 0) {
        ull cur = ((ull)remv32[gi * 2 + 1] << 32) | remv32[gi * 2];
        unsigned int clo = __builtin_amdgcn_readfirstlane((unsigned int)cur);
        unsigned int chi = __builtin_amdgcn_readfirstlane((unsigned int)(cur >> 32));
        cur = ((ull)chi << 32) | clo;
        ull mrow = tileRows[(gi * 64 + lane) * TRS + gi];
        const unsigned int ml = (unsigned int)mrow;
        const unsigned int mh = (unsigned int)(mrow >> 32);
        const ull validm = (g == WORDS - 1) ? 0xFFFFull : ~0ull;
        ull rem = (~cur) & validm;
        while (rem) {
          int b = __ffsll((long long)rem) - 1;
          b = __builtin_amdgcn_readfirstlane(b);
          ull m = ((ull)(unsigned int)__builtin_amdgcn_readlane((int)mh, b) << 32) |
                  (unsigned int)__builtin_amdgcn_readlane((int)ml, b);
          cur |= m;
          ull above = (b == 63) ? 0ull : (~0ull << (b + 1));
          rem = (~cur) & rem & above;
        }
        ull kb = (~cur) & validm;
        if (lane == 0) keepwords[g] = kb;
        int kc = kcLds;
        if ((kb >> lane) & 1ull) {
          int ofs = __popcll(lane ? (kb & ((1ull << lane) - 1ull)) : 0ull);
          klist[kc + ofs] = g * 64 + lane;
          newk[ofs] = gi * 64 + lane;   // local row index for FU
        }
        if (lane == 0) {
          int nk = __popcll(kb);
          nkLds = nk;
          kcLds = kc + nk;
          doneLds = (kc + nk >= TOPK2) ? 1 : 0;
        }
      }
      __syncthreads();
      if (doneLds) break;
      // forward-update remaining tile words with newly kept rows (LDS only)
      if (gi + 1 < TW) {
        int w = tid & 7, k0 = tid >> 3;
        int nk = nkLds;
        if (w > gi && w < TW) {
          ull acc = 0;
          for (int kk = k0; kk < nk; kk += 32) acc |= tileRows[newk[kk] * TRS + w];
          if (acc) {
            atomicOr(&remv32[w * 2], (unsigned int)acc);
            atomicOr(&remv32[w * 2 + 1], (unsigned int)(acc >> 32));
          }
        }
      }
      __syncthreads();
    }
    if (doneLds) break;
  }
}

// ---------------- compact kept boxes, sigmoid scores, write output ---------
__global__ __launch_bounds__(256) void finalize_kernel(const ull* __restrict__ keepwords,
                                                       const double* __restrict__ sBox,
                                                       const double* __restrict__ sLog,
                                                       float* __restrict__ out) {
  __shared__ int pref[WORDS];
  int t = threadIdx.x;
  if (t == 0) {
    int s = 0;
    for (int w = 0; w < WORDS; ++w) {
      pref[w] = s;
      s += __popcll(keepwords[w]);
    }
  }
  __syncthreads();
  if (t < WORDS) {
    ull kb = keepwords[t];
    int base = pref[t];
    while (kb) {
      int b = __ffsll((long long)kb) - 1;
      kb &= kb - 1;
      if (base < TOPK2) {
        int i = t * 64 + b;
        out[base * 4 + 0] = (float)sBox[(size_t)i * 4 + 0];
        out[base * 4 + 1] = (float)sBox[(size_t)i * 4 + 1];
        out[base * 4 + 2] = (float)sBox[(size_t)i * 4 + 2];
        out[base * 4 + 3] = (float)sBox[(size_t)i * 4 + 3];
        double L = sLog[i];
        out[TOPK2 * 4 + base] = (float)(1.0 / (1.0 + exp(-L)));
      }
      ++base;
    }
  }
}

// ---------------------------------------------------------------------------
extern "C" void kernel_launch(void* const* d_in, const int* in_sizes, int n_in,
                              void* d_out, int out_size, void* d_ws, size_t ws_size,
                              hipStream_t stream) {
  // inputs: 0 image(unused) 1 feat 2 rpn_w 3 rpn_b 4 cls_w 5 cls_b 6 box_w 7 box_b
  const float* feat  = (const float*)d_in[1];
  const float* rpn_w = (const float*)d_in[2];
  const float* rpn_b = (const float*)d_in[3];
  const float* cls_w = (const float*)d_in[4];
  const float* cls_b = (const float*)d_in[5];
  const float* box_w = (const float*)d_in[6];
  const float* box_b = (const float*)d_in[7];
  float* out = (float*)d_out;

  // workspace layout (bytes, all 16B aligned); total ~34.44 MB
  char* ws = (char*)d_ws;
  double* part     = (double*)(ws);                 // 2*512*2500*8 = 20,480,000
  double* logits   = (double*)(ws + 20480000);      // 22500*8     =    180,000
  double* boxesAll = (double*)(ws + 20660000);      // 22500*4*8   =    720,000
  int*    ranks    = (int*)   (ws + 21380000);      // 22500*4     =     90,000
  double* sBox     = (double*)(ws + 21470000);      // 10000*4*8   =    320,000
  double* sLog     = (double*)(ws + 21790000);      // 10000*8     =     80,000
  ull*    mask     = (ull*)   (ws + 21870000);      // 10000*157*8 = 12,560,000
  ull*    keepw    = (ull*)   (ws + 34430000);      // 157*8       =      1,256

  hipMemsetAsync(d_out, 0, (TOPK2 * 4 + TOPK2) * sizeof(float), stream);
  hipMemsetAsync(ranks, 0, NBOX * sizeof(int), stream);
  hipMemsetAsync(keepw, 0, WORDS * sizeof(ull), stream);  // early-exit tail

  conv_gemm<<<dim3(40, 8, 2), 256, 0, stream>>>(feat, rpn_w, part);
  heads_kernel<<<10, 256, 0, stream>>>(part, rpn_b, cls_w, cls_b, box_w, box_b,
                                       logits, boxesAll, out + TOPK2 * 5);
  rank_count<<<dim3(88, 11), 256, 0, stream>>>(logits, ranks);
  scatter_topk<<<88, 256, 0, stream>>>(logits, boxesAll, ranks, sLog, sBox);
  iou_mask<<<dim3(WORDS, 40), 256, 0, stream>>>(sBox, mask);
  nms_scan<<<1, 256, 0, stream>>>(mask, keepw);
  finalize_kernel<<<1, 256, 0, stream>>>(keepw, sBox, sLog, out);
}

// Round 7
// 1104.259 us; speedup vs baseline: 1.5284x; 1.0977x over previous
//
#include <hip/hip_runtime.h>
#include <cstdint>
#include <cstddef>

// ---------------------------------------------------------------------------
// RPN pipeline, fp64-accurate (ordering-critical: top-k rank + NMS decisions).
// fp32 inputs; all reductions accumulate in double (fp32*fp32 exact in f64).
// ---------------------------------------------------------------------------

typedef unsigned long long ull;
typedef double d4 __attribute__((ext_vector_type(4)));

#define NANCH 9
#define NPIX  2500      // 50*50
#define CIN   512
#define COUT  512
#define KTOT  4608      // 512*9
#define KSEG  2304      // KTOT/2
#define NBOX  22500     // 2500*9
#define TOPK1 10000
#define TOPK2 2000
#define WORDS 157       // ceil(10000/64)

// ---------------- conv 3x3 as implicit-im2col GEMM, f64 MFMA ---------------
// grid (40 p-tiles, 8 co-tiles, 2 k-segments), block 256 = 4 waves.
// Each wave computes a 32p x 32co tile as 2x2 v_mfma_f64_16x16x4_f64 tiles.
// C/D register->(row,col) mapping is NOT assumed: a one-off probe MFMA with
// injective values (D[m][n] = (m+1) + 1000*(n+1), exact in f64) is decoded
// per lane to learn where each acc element belongs. This is robust to any
// bijective C/D layout / operand-role convention (R6 failed on a guessed
// layout; f64 was never in the HW-verified dtype list).
__global__ __launch_bounds__(256) void conv_gemm(const float* __restrict__ feat,
                                                 const float* __restrict__ w,
                                                 double* __restrict__ part) {
  const int p0  = blockIdx.x * 64;
  const int co0 = blockIdx.y * 64;
  const int z   = blockIdx.z;
  const int kseg0 = z * KSEG;
  __shared__ double As[16][68];   // [k][p]  f64, padded stride
  __shared__ double Bs[16][68];   // [k][co] f64
  const int tid  = threadIdx.x;
  const int lane = tid & 63;
  const int wave = tid >> 6;
  const int quad = lane >> 4;
  const int l16  = lane & 15;
  const int wp = (wave & 1) * 32;   // wave p offset in tile
  const int wc = (wave >> 1) * 32;  // wave co offset in tile
  // staging indices (same pattern as the verified VALU version)
  const int coA = tid >> 2;          // 0..63  (weight row)
  const int kA  = (tid & 3) * 4;     // 0,4,8,12
  const int plB = tid & 63;          // p local
  const int kB0 = tid >> 6;          // 0..3
  const int pB = p0 + plB;
  const int py = pB / 50, px = pB - py * 50;

  // ---- layout probe: learn the C/D register->(m,n) mapping ----
  int pmap[4];
  {
    double av_p = (quad == 0) ? (double)(l16 + 1) : (quad == 1 ? 1.0 : 0.0);
    double bv_p = (quad == 0) ? 1.0 : (quad == 1 ? (double)(1000 * (l16 + 1)) : 0.0);
    d4 dp = (d4){0.0, 0.0, 0.0, 0.0};
    dp = __builtin_amdgcn_mfma_f64_16x16x4f64(av_p, bv_p, dp, 0, 0, 0);
#pragma unroll
    for (int r = 0; r < 4; ++r) {
      int iv = (int)(dp[r] + 0.5);
      int mm = iv % 1000 - 1;   // p-id within the 16 block
      int nn = iv / 1000 - 1;   // co-id within the 16 block
      pmap[r] = (mm & 255) | (nn << 8);
    }
  }

  d4 acc[2][2];
#pragma unroll
  for (int i = 0; i < 2; ++i)
#pragma unroll
    for (int j = 0; j < 2; ++j) acc[i][j] = (d4){0.0, 0.0, 0.0, 0.0};

  // prologue: load chunk 0 into regs
  float4 wa = *(const float4*)(w + (size_t)(co0 + coA) * KTOT + (kseg0 + kA));
  float fb[4];
#pragma unroll
  for (int jj = 0; jj < 4; ++jj) {
    int k = kseg0 + kB0 + 4 * jj;
    int ci = k / 9, r = k - ci * 9, ky = r / 3, kx = r - ky * 3;
    int yy = py + ky - 1, xx = px + kx - 1;
    float v = 0.0f;
    if (pB < NPIX && yy >= 0 && yy < 50 && xx >= 0 && xx < 50)
      v = feat[ci * NPIX + yy * 50 + xx];
    fb[jj] = v;
  }

  for (int k0 = 0; k0 < KSEG; k0 += 16) {
    __syncthreads();   // previous chunk's compute done -> LDS reusable
    Bs[kA + 0][coA] = (double)wa.x;
    Bs[kA + 1][coA] = (double)wa.y;
    Bs[kA + 2][coA] = (double)wa.z;
    Bs[kA + 3][coA] = (double)wa.w;
#pragma unroll
    for (int jj = 0; jj < 4; ++jj) As[kB0 + 4 * jj][plB] = (double)fb[jj];
    __syncthreads();
    // prefetch chunk k0+16 (retires during the MFMA burst below)
    int kn = k0 + 16;
    if (kn < KSEG) {
      wa = *(const float4*)(w + (size_t)(co0 + coA) * KTOT + (kseg0 + kn + kA));
#pragma unroll
      for (int jj = 0; jj < 4; ++jj) {
        int k = kseg0 + kn + kB0 + 4 * jj;
        int ci = k / 9, r = k - ci * 9, ky = r / 3, kx = r - ky * 3;
        int yy = py + ky - 1, xx = px + kx - 1;
        float v = 0.0f;
        if (pB < NPIX && yy >= 0 && yy < 50 && xx >= 0 && xx < 50)
          v = feat[ci * NPIX + yy * 50 + xx];
        fb[jj] = v;
      }
    }
    // MFMA burst: 4 k-steps x 4 tile-MFMAs
#pragma unroll
    for (int kk = 0; kk < 16; kk += 4) {
      double av0 = As[kk + quad][wp + l16];
      double av1 = As[kk + quad][wp + 16 + l16];
      double bv0 = Bs[kk + quad][wc + l16];
      double bv1 = Bs[kk + quad][wc + 16 + l16];
      acc[0][0] = __builtin_amdgcn_mfma_f64_16x16x4f64(av0, bv0, acc[0][0], 0, 0, 0);
      acc[0][1] = __builtin_amdgcn_mfma_f64_16x16x4f64(av0, bv1, acc[0][1], 0, 0, 0);
      acc[1][0] = __builtin_amdgcn_mfma_f64_16x16x4f64(av1, bv0, acc[1][0], 0, 0, 0);
      acc[1][1] = __builtin_amdgcn_mfma_f64_16x16x4f64(av1, bv1, acc[1][1], 0, 0, 0);
    }
  }
  // epilogue: probe-decoded scatter. Element r of acc[ti][tj] holds the
  // product for p = p0+wp+ti*16+pm, co = co0+wc+tj*16+pn.
  double* basez = part + (size_t)z * COUT * NPIX;
#pragma unroll
  for (int ti = 0; ti < 2; ++ti)
#pragma unroll
    for (int tj = 0; tj < 2; ++tj) {
#pragma unroll
      for (int r = 0; r < 4; ++r) {
        int mm = pmap[r] & 255, nn = pmap[r] >> 8;
        int p  = p0 + wp + ti * 16 + mm;
        int co = co0 + wc + tj * 16 + nn;
        if (p < NPIX) basez[(size_t)co * NPIX + p] = acc[ti][tj][r];
      }
    }
}

// ---------------- heads: relu(conv)+bias, cls+box 1x1 convs, decode --------
__global__ __launch_bounds__(256) void heads_kernel(
    const double* __restrict__ part, const float* __restrict__ rpn_b,
    const float* __restrict__ cls_w, const float* __restrict__ cls_b,
    const float* __restrict__ box_w, const float* __restrict__ box_b,
    double* __restrict__ logits, double* __restrict__ boxesAll,
    float* __restrict__ out_cls) {
  int p = blockIdx.x * blockDim.x + threadIdx.x;
  bool act = p < NPIX;
  int pp = act ? p : 0;
  double accC[9];
  double accB[36];
#pragma unroll
  for (int a = 0; a < 9; ++a) accC[a] = 0.0;
#pragma unroll
  for (int c = 0; c < 36; ++c) accB[c] = 0.0;
  const double* part1 = part + (size_t)COUT * NPIX;
  for (int co = 0; co < CIN; ++co) {
    double v = part[(size_t)co * NPIX + pp] + part1[(size_t)co * NPIX + pp] +
               (double)rpn_b[co];
    v = v > 0.0 ? v : 0.0;
#pragma unroll
    for (int a = 0; a < 9; ++a) accC[a] += (double)cls_w[a * CIN + co] * v;
#pragma unroll
    for (int c = 0; c < 36; ++c) accB[c] += (double)box_w[c * CIN + co] * v;
  }
  if (!act) return;
  int y = p / 50, x = p - y * 50;
  double sx = 16.0 * (double)x, sy = 16.0 * (double)y;
  const double scs[3] = {128.0, 256.0, 512.0};
  const double ars[3] = {0.5, 1.0, 2.0};
#pragma unroll
  for (int a = 0; a < 9; ++a) {
    double ar = ars[a / 3], sc = scs[a - (a / 3) * 3];
    double hr = sqrt(ar), wr = 1.0 / hr;
    double wv = wr * sc, hv = hr * sc;
    // jnp.round == round-half-even == rint under default rounding mode
    double bx0 = rint(-wv * 0.5), by0 = rint(-hv * 0.5);
    double bx1 = rint(wv * 0.5), by1 = rint(hv * 0.5);
    double a0 = sx + bx0, a1 = sy + by0, a2 = sx + bx1, a3 = sy + by1;
    double wA = a2 - a0, hA = a3 - a1;
    double cx = a0 + 0.5 * wA, cy = a1 + 0.5 * hA;
    double dx = accB[a * 4 + 0] + (double)box_b[a * 4 + 0];
    double dy = accB[a * 4 + 1] + (double)box_b[a * 4 + 1];
    double dw = accB[a * 4 + 2] + (double)box_b[a * 4 + 2];
    double dh = accB[a * 4 + 3] + (double)box_b[a * 4 + 3];
    double pcx = wA * dx + cx, pcy = hA * dy + cy;
    double pw = exp(dw) * wA, ph = exp(dh) * hA;
    double b0 = pcx - 0.5 * pw, b1 = pcy - 0.5 * ph;
    double b2 = pcx + 0.5 * pw, b3 = pcy + 0.5 * ph;
    b0 = fmin(fmax(b0, 0.0), 800.0);
    b1 = fmin(fmax(b1, 0.0), 800.0);
    b2 = fmin(fmax(b2, 0.0), 800.0);
    b3 = fmin(fmax(b3, 0.0), 800.0);
    int idx = p * 9 + a;
    boxesAll[(size_t)idx * 4 + 0] = b0;
    boxesAll[(size_t)idx * 4 + 1] = b1;
    boxesAll[(size_t)idx * 4 + 2] = b2;
    boxesAll[(size_t)idx * 4 + 3] = b3;
    double L = accC[a] + (double)cls_b[a];
    logits[idx] = L;
    out_cls[idx] = (float)L;
  }
}

// ---------------- exact stable descending rank (== jax.lax.top_k order) ---
__global__ __launch_bounds__(256) void rank_count(const double* __restrict__ logits,
                                                  int* __restrict__ ranks) {
  __shared__ double Ls[2048];
  int i = blockIdx.x * 256 + threadIdx.x;
  int j0 = blockIdx.y * 2048;
  int jn = NBOX - j0;
  if (jn > 2048) jn = 2048;
  for (int t = threadIdx.x; t < jn; t += 256) Ls[t] = logits[j0 + t];
  __syncthreads();
  if (i >= NBOX) return;
  double Li = logits[i];
  int cnt = 0;
  for (int t = 0; t < jn; ++t) {
    double Lj = Ls[t];
    int j = j0 + t;
    cnt += (Lj > Li || (Lj == Li && j < i)) ? 1 : 0;
  }
  atomicAdd(&ranks[i], cnt);
}

__global__ __launch_bounds__(256) void scatter_topk(const double* __restrict__ logits,
                                                    const double* __restrict__ boxesAll,
                                                    const int* __restrict__ ranks,
                                                    double* __restrict__ sLog,
                                                    double* __restrict__ sBox) {
  int i = blockIdx.x * 256 + threadIdx.x;
  if (i >= NBOX) return;
  int r = ranks[i];
  if (r < TOPK1) {
    sLog[r] = logits[i];
    sBox[(size_t)r * 4 + 0] = boxesAll[(size_t)i * 4 + 0];
    sBox[(size_t)r * 4 + 1] = boxesAll[(size_t)i * 4 + 1];
    sBox[(size_t)r * 4 + 2] = boxesAll[(size_t)i * 4 + 2];
    sBox[(size_t)r * 4 + 3] = boxesAll[(size_t)i * 4 + 3];
  }
}

// ---------------- pairwise IoU suppression bitmask (upper triangle) --------
// grid (157 i-tiles, 40 word-tiles), block 256 = 64 i x 4 words.
__global__ __launch_bounds__(256) void iou_mask(const double* __restrict__ sb,
                                                ull* __restrict__ mask) {
  const int it = blockIdx.x;
  const int wt = blockIdx.y;
  if (wt * 4 + 3 < it) return;  // block only needed for words >= i/64
  __shared__ double ib[64][4];
  __shared__ double jb[256][4];
  const int tid = threadIdx.x;
  {
    int ii = it * 64 + (tid >> 2);
    int d = tid & 3;
    ib[tid >> 2][d] = (ii < TOPK1) ? sb[(size_t)ii * 4 + d] : 0.0;
  }
  for (int t = tid; t < 1024; t += 256) {
    int jj = wt * 256 + (t >> 2);
    jb[t >> 2][t & 3] = (jj < TOPK1) ? sb[(size_t)jj * 4 + (t & 3)] : 0.0;
  }
  __syncthreads();
  const int il = tid & 63, wl = tid >> 6;
  const int i = it * 64 + il;
  const int word = wt * 4 + wl;
  if (i >= TOPK1 || word >= WORDS || word < (i >> 6)) return;
  const double x0 = ib[il][0], y0 = ib[il][1], x1 = ib[il][2], y1 = ib[il][3];
  const double areai = (x1 - x0) * (y1 - y0);
  ull bits = 0;
  const int jbase = word * 64;
  for (int b = 0; b < 64; ++b) {
    int j = jbase + b;
    if (j <= i || j >= TOPK1) continue;
    int jl = wl * 64 + b;
    double u0 = jb[jl][0], u1 = jb[jl][1], u2 = jb[jl][2], u3 = jb[jl][3];
    double xl = fmax(x0, u0), yt = fmax(y0, u1);
    double xr = fmin(x1, u2), yb = fmin(y1, u3);
    double iw = xr - xl, ih = yb - yt;
    iw = iw > 0.0 ? iw : 0.0;
    ih = ih > 0.0 ? ih : 0.0;
    double inter = iw * ih;
    double aj = (u2 - u0) * (u3 - u1);
    double un = areai + aj - inter;
    // reference: inter/un > 0.7 (0/0 -> NaN -> false). Multiply form matches.
    if (inter > 0.7 * un) bits |= 1ull << b;
  }
  mask[(size_t)i * WORDS + word] = bits;
}

// ---------------- tiled greedy-NMS scan, LDS-resident tile -----------------
#define NTILE 8
#define TRS   10    // padded ull stride for tileRows (8 words + 2 pad)
#define KCAP  2112

__global__ __launch_bounds__(256) void nms_scan(const ull* __restrict__ mask,
                                                ull* __restrict__ keepwords) {
  __shared__ ull tileRows[512 * TRS];        // 40,960 B
  __shared__ int klist[KCAP];                // kept global indices (rank order)
  __shared__ ull remvPart[32][NTILE + 1];    // column-OR partials
  __shared__ unsigned int remv32[NTILE * 2]; // removal words (lo/hi pairs)
  __shared__ int newk[64];                   // this group's kept local rows
  __shared__ int kcLds, nkLds, doneLds;
  const int tid = threadIdx.x;
  const int lane = tid & 63;
  const int wave = tid >> 6;
  if (tid == 0) { kcLds = 0; nkLds = 0; doneLds = 0; }
  __syncthreads();

  for (int T = 0; T < (WORDS + NTILE - 1) / NTILE; ++T) {
    const int G0 = T * NTILE;
    const int TW = (WORDS - G0 < NTILE) ? (WORDS - G0) : NTILE;
    const int kc0 = kcLds;
    // ---- Phase A1: stage tile rows (512 x TW words) into LDS ----
#pragma unroll
    for (int pass = 0; pass < 8; ++pass) {
      int lr = pass * 64 + (tid >> 2);   // local row 0..511
      int w  = (tid & 3) * 2;            // word pair
      int gr = G0 * 64 + lr;             // global row
      ull v0 = 0, v1 = 0;
      if (gr < TOPK1) {
        const ull* row = mask + (size_t)gr * WORDS + G0;
        if (w < TW)     v0 = row[w];
        if (w + 1 < TW) v1 = row[w + 1];
      }
      tileRows[lr * TRS + w]     = v0;
      tileRows[lr * TRS + w + 1] = v1;
    }
    // ---- Phase A2: base removal words = OR over previously-kept rows ----
    {
      int w = tid & 7, stripe = tid >> 3;   // 32 stripes x 8 words
      ull acc = 0;
      if (w < TW) {
        int t = stripe;
        for (; t + 224 < kc0; t += 256) {
          ull a0 = mask[(size_t)klist[t      ] * WORDS + G0 + w];
          ull a1 = mask[(size_t)klist[t +  32] * WORDS + G0 + w];
          ull a2 = mask[(size_t)klist[t +  64] * WORDS + G0 + w];
          ull a3 = mask[(size_t)klist[t +  96] * WORDS + G0 + w];
          ull a4 = mask[(size_t)klist[t + 128] * WORDS + G0 + w];
          ull a5 = mask[(size_t)klist[t + 160] * WORDS + G0 + w];
          ull a6 = mask[(size_t)klist[t + 192] * WORDS + G0 + w];
          ull a7 = mask[(size_t)klist[t + 224] * WORDS + G0 + w];
          acc |= ((a0 | a1) | (a2 | a3)) | ((a4 | a5) | (a6 | a7));
        }
        for (; t < kc0; t += 32) acc |= mask[(size_t)klist[t] * WORDS + G0 + w];
      }
      remvPart[stripe][w] = acc;
    }
    __syncthreads();
    if (tid < NTILE) {
      ull r = 0;
#pragma unroll
      for (int s = 0; s < 32; ++s) r |= remvPart[s][tid];
      remv32[tid * 2]     = (unsigned int)r;
      remv32[tid * 2 + 1] = (unsigned int)(r >> 32);
    }
    __syncthreads();
    // ---- Phase B: sequential resolve of the tile's groups (LDS only) ----
    for (int gi = 0; gi < TW; ++gi) {
      const int g = G0 + gi;
      if (wave == 0) {
        ull cur = ((ull)remv32[gi * 2 + 1] << 32) | remv32[gi * 2];
        unsigned int clo = __builtin_amdgcn_readfirstlane((unsigned int)cur);
        unsigned int chi = __builtin_amdgcn_readfirstlane((unsigned int)(cur >> 32));
        cur = ((ull)chi << 32) | clo;
        ull mrow = tileRows[(gi * 64 + lane) * TRS + gi];
        const unsigned int ml = (unsigned int)mrow;
        const unsigned int mh = (unsigned int)(mrow >> 32);
        const ull validm = (g == WORDS - 1) ? 0xFFFFull : ~0ull;
        ull rem = (~cur) & validm;
        while (rem) {
          int b = __ffsll((long long)rem) - 1;
          b = __builtin_amdgcn_readfirstlane(b);
          ull m = ((ull)(unsigned int)__builtin_amdgcn_readlane((int)mh, b) << 32) |
                  (unsigned int)__builtin_amdgcn_readlane((int)ml, b);
          cur |= m;
          ull above = (b == 63) ? 0ull : (~0ull << (b + 1));
          rem = (~cur) & rem & above;
        }
        ull kb = (~cur) & validm;
        if (lane == 0) keepwords[g] = kb;
        int kc = kcLds;
        if ((kb >> lane) & 1ull) {
          int ofs = __popcll(lane ? (kb & ((1ull << lane) - 1ull)) : 0ull);
          klist[kc + ofs] = g * 64 + lane;
          newk[ofs] = gi * 64 + lane;   // local row index for FU
        }
        if (lane == 0) {
          int nk = __popcll(kb);
          nkLds = nk;
          kcLds = kc + nk;
          doneLds = (kc + nk >= TOPK2) ? 1 : 0;
        }
      }
      __syncthreads();
      if (doneLds) break;
      // forward-update remaining tile words with newly kept rows (LDS only)
      if (gi + 1 < TW) {
        int w = tid & 7, k0 = tid >> 3;
        int nk = nkLds;
        if (w > gi && w < TW) {
          ull acc = 0;
          for (int kk = k0; kk < nk; kk += 32) acc |= tileRows[newk[kk] * TRS + w];
          if (acc) {
            atomicOr(&remv32[w * 2], (unsigned int)acc);
            atomicOr(&remv32[w * 2 + 1], (unsigned int)(acc >> 32));
          }
        }
      }
      __syncthreads();
    }
    if (doneLds) break;
  }
}

// ---------------- compact kept boxes, sigmoid scores, write output ---------
__global__ __launch_bounds__(256) void finalize_kernel(const ull* __restrict__ keepwords,
                                                       const double* __restrict__ sBox,
                                                       const double* __restrict__ sLog,
                                                       float* __restrict__ out) {
  __shared__ int pref[WORDS];
  int t = threadIdx.x;
  if (t == 0) {
    int s = 0;
    for (int w = 0; w < WORDS; ++w) {
      pref[w] = s;
      s += __popcll(keepwords[w]);
    }
  }
  __syncthreads();
  if (t < WORDS) {
    ull kb = keepwords[t];
    int base = pref[t];
    while (kb) {
      int b = __ffsll((long long)kb) - 1;
      kb &= kb - 1;
      if (base < TOPK2) {
        int i = t * 64 + b;
        out[base * 4 + 0] = (float)sBox[(size_t)i * 4 + 0];
        out[base * 4 + 1] = (float)sBox[(size_t)i * 4 + 1];
        out[base * 4 + 2] = (float)sBox[(size_t)i * 4 + 2];
        out[base * 4 + 3] = (float)sBox[(size_t)i * 4 + 3];
        double L = sLog[i];
        out[TOPK2 * 4 + base] = (float)(1.0 / (1.0 + exp(-L)));
      }
      ++base;
    }
  }
}

// ---------------------------------------------------------------------------
extern "C" void kernel_launch(void* const* d_in, const int* in_sizes, int n_in,
                              void* d_out, int out_size, void* d_ws, size_t ws_size,
                              hipStream_t stream) {
  // inputs: 0 image(unused) 1 feat 2 rpn_w 3 rpn_b 4 cls_w 5 cls_b 6 box_w 7 box_b
  const float* feat  = (const float*)d_in[1];
  const float* rpn_w = (const float*)d_in[2];
  const float* rpn_b = (const float*)d_in[3];
  const float* cls_w = (const float*)d_in[4];
  const float* cls_b = (const float*)d_in[5];
  const float* box_w = (const float*)d_in[6];
  const float* box_b = (const float*)d_in[7];
  float* out = (float*)d_out;

  // workspace layout (bytes, all 16B aligned); total ~34.44 MB
  char* ws = (char*)d_ws;
  double* part     = (double*)(ws);                 // 2*512*2500*8 = 20,480,000
  double* logits   = (double*)(ws + 20480000);      // 22500*8     =    180,000
  double* boxesAll = (double*)(ws + 20660000);      // 22500*4*8   =    720,000
  int*    ranks    = (int*)   (ws + 21380000);      // 22500*4     =     90,000
  double* sBox     = (double*)(ws + 21470000);      // 10000*4*8   =    320,000
  double* sLog     = (double*)(ws + 21790000);      // 10000*8     =     80,000
  ull*    mask     = (ull*)   (ws + 21870000);      // 10000*157*8 = 12,560,000
  ull*    keepw    = (ull*)   (ws + 34430000);      // 157*8       =      1,256

  hipMemsetAsync(d_out, 0, (TOPK2 * 4 + TOPK2) * sizeof(float), stream);
  hipMemsetAsync(ranks, 0, NBOX * sizeof(int), stream);
  hipMemsetAsync(keepw, 0, WORDS * sizeof(ull), stream);  // early-exit tail

  conv_gemm<<<dim3(40, 8, 2), 256, 0, stream>>>(feat, rpn_w, part);
  heads_kernel<<<10, 256, 0, stream>>>(part, rpn_b, cls_w, cls_b, box_w, box_b,
                                       logits, boxesAll, out + TOPK2 * 5);
  rank_count<<<dim3(88, 11), 256, 0, stream>>>(logits, ranks);
  scatter_topk<<<88, 256, 0, stream>>>(logits, boxesAll, ranks, sLog, sBox);
  iou_mask<<<dim3(WORDS, 40), 256, 0, stream>>>(sBox, mask);
  nms_scan<<<1, 256, 0, stream>>>(mask, keepw);
  finalize_kernel<<<1, 256, 0, stream>>>(keepw, sBox, sLog, out);
}